// Round 3
// baseline (234.877 us; speedup 1.0000x reference)
//
#include <hip/hip_runtime.h>
#include <stdint.h>

#define IN_C   16
#define OUT_C  16
#define EDGE_DIM 8
#define HID    32
#define T_STRIDE 528  // 33*16 floats per node: rows j=0..31 -> sum_i x_i*W2[j,i,o]; row 32 -> sum_i x_i*b2[i,o]

// ---------------- main path kernels ----------------

// T[n, j*16+o] = sum_i x[n,i]*W2[j,i*16+o];  T[n, 512+o] = sum_i x[n,i]*b2[i*16+o]
__global__ __launch_bounds__(512) void nnconv_T(
    const float* __restrict__ x, const float* __restrict__ W2,
    const float* __restrict__ b2, float* __restrict__ T, int n_nodes)
{
    int q = threadIdx.x;           // 0..511
    int j = q >> 4, o = q & 15;
    float w[IN_C], wb[IN_C];
    #pragma unroll
    for (int i = 0; i < IN_C; ++i) w[i]  = W2[j * 256 + i * 16 + o];
    #pragma unroll
    for (int i = 0; i < IN_C; ++i) wb[i] = b2[i * 16 + o];
    for (int n = blockIdx.x; n < n_nodes; n += gridDim.x) {
        const float* xr = x + (size_t)n * IN_C;
        float a = 0.f, ab = 0.f;
        #pragma unroll
        for (int i = 0; i < IN_C; ++i) {
            float xi = xr[i];
            a  = fmaf(xi, w[i],  a);
            ab = fmaf(xi, wb[i], ab);
        }
        T[(size_t)n * T_STRIDE + q] = a;
        if (q < 16) T[(size_t)n * T_STRIDE + 512 + q] = ab;
    }
}

__global__ __launch_bounds__(256) void nnconv_zero(int* __restrict__ p, int n)
{
    int t = blockIdx.x * blockDim.x + threadIdx.x;
    for (int i = t; i < n; i += gridDim.x * blockDim.x) p[i] = 0;
}

__global__ __launch_bounds__(256) void nnconv_count2(
    const int* __restrict__ eidx, int* __restrict__ cnt_row,
    int* __restrict__ cnt_col, int n_edges)
{
    int e = blockIdx.x * blockDim.x + threadIdx.x;
    if (e >= n_edges) return;
    atomicAdd(&cnt_row[eidx[e]], 1);
    atomicAdd(&cnt_col[eidx[n_edges + e]], 1);
}

// block 0: scan cnt_row->base_row ; block 1: scan cnt_col->base_col (exclusive)
__global__ __launch_bounds__(1024) void nnconv_scan2(
    const int* __restrict__ cnt_row, int* __restrict__ base_row,
    const int* __restrict__ cnt_col, int* __restrict__ base_col, int n)
{
    const int* cnt = (blockIdx.x == 0) ? cnt_row : cnt_col;
    int* base      = (blockIdx.x == 0) ? base_row : base_col;
    __shared__ int sums[1024];
    int t = threadIdx.x;
    int chunk = (n + 1023) >> 10;
    int lo = t * chunk; if (lo > n) lo = n;
    int hi = lo + chunk; if (hi > n) hi = n;
    int s = 0;
    for (int i = lo; i < hi; ++i) s += cnt[i];
    sums[t] = s;
    __syncthreads();
    for (int off = 1; off < 1024; off <<= 1) {
        int v = (t >= off) ? sums[t - off] : 0;
        __syncthreads();
        sums[t] += v;
        __syncthreads();
    }
    int run = sums[t] - s;
    for (int i = lo; i < hi; ++i) { base[i] = run; run += cnt[i]; }
}

// per edge: compute col-sorted position pc and row-sorted slot; pack (e, slot, c)
__global__ __launch_bounds__(256) void nnconv_build(
    const int* __restrict__ eidx,
    const int* __restrict__ base_row, int* __restrict__ cur_row,
    const int* __restrict__ base_col, int* __restrict__ cur_col,
    uint64_t* __restrict__ packed, int n_edges)
{
    int e = blockIdx.x * blockDim.x + threadIdx.x;
    if (e >= n_edges) return;
    int r = eidx[e], c = eidx[n_edges + e];
    int slot = base_row[r] + atomicAdd(&cur_row[r], 1);
    int pc   = base_col[c] + atomicAdd(&cur_col[c], 1);
    packed[pc] = (uint64_t)(uint32_t)e
               | ((uint64_t)(uint32_t)slot << 20)
               | ((uint64_t)(uint32_t)c << 40);
}

// thread t (col-sorted order): h-MLP, msg = h @ T[c] + B[c], store at row-slot
__global__ __launch_bounds__(256) void nnconv_edge_T(
    const float* __restrict__ pseudo,
    const float* __restrict__ W1, const float* __restrict__ b1,
    const float* __restrict__ T, const uint64_t* __restrict__ packed,
    float* __restrict__ msg, int n_edges)
{
    int t = blockIdx.x * blockDim.x + threadIdx.x;
    if (t >= n_edges) return;
    uint64_t pk = packed[t];
    int e    = (int)(pk & 0xFFFFF);
    int slot = (int)((pk >> 20) & 0xFFFFF);
    int c    = (int)(pk >> 40);

    float p[EDGE_DIM];
    const float4* pp = reinterpret_cast<const float4*>(pseudo + (size_t)e * EDGE_DIM);
    float4 p0 = pp[0], p1 = pp[1];
    p[0]=p0.x; p[1]=p0.y; p[2]=p0.z; p[3]=p0.w;
    p[4]=p1.x; p[5]=p1.y; p[6]=p1.z; p[7]=p1.w;

    float h[HID];
    #pragma unroll
    for (int j = 0; j < HID; ++j) {
        float a = b1[j];
        #pragma unroll
        for (int k = 0; k < EDGE_DIM; ++k)
            a = fmaf(p[k], W1[k * HID + j], a);   // W1 wave-uniform -> scalar loads
        h[j] = a > 0.f ? a : 0.f;
    }

    const float4* Tp = reinterpret_cast<const float4*>(T + (size_t)c * T_STRIDE);
    float4 m0 = Tp[128], m1 = Tp[129], m2 = Tp[130], m3 = Tp[131];  // B[c] row
    #pragma unroll
    for (int j = 0; j < HID; ++j) {
        float hj = h[j];
        float4 a = Tp[j*4+0], b = Tp[j*4+1], cc = Tp[j*4+2], d = Tp[j*4+3];
        m0.x = fmaf(hj, a.x, m0.x);  m0.y = fmaf(hj, a.y, m0.y);
        m0.z = fmaf(hj, a.z, m0.z);  m0.w = fmaf(hj, a.w, m0.w);
        m1.x = fmaf(hj, b.x, m1.x);  m1.y = fmaf(hj, b.y, m1.y);
        m1.z = fmaf(hj, b.z, m1.z);  m1.w = fmaf(hj, b.w, m1.w);
        m2.x = fmaf(hj, cc.x, m2.x); m2.y = fmaf(hj, cc.y, m2.y);
        m2.z = fmaf(hj, cc.z, m2.z); m2.w = fmaf(hj, cc.w, m2.w);
        m3.x = fmaf(hj, d.x, m3.x);  m3.y = fmaf(hj, d.y, m3.y);
        m3.z = fmaf(hj, d.z, m3.z);  m3.w = fmaf(hj, d.w, m3.w);
    }
    float4* mp = reinterpret_cast<float4*>(msg + (size_t)slot * OUT_C);
    mp[0] = m0; mp[1] = m1; mp[2] = m2; mp[3] = m3;
}

// wave per node: out = bias + x@root + sum of msg slots
__global__ __launch_bounds__(256) void nnconv_gather_root(
    const float* __restrict__ msg, const int* __restrict__ base,
    const int* __restrict__ cnt, const float* __restrict__ x,
    const float* __restrict__ root, const float* __restrict__ bias,
    float* __restrict__ out, int n_nodes)
{
    int wave = threadIdx.x >> 6, lane = threadIdx.x & 63;
    int n = blockIdx.x * 4 + wave;
    if (n >= n_nodes) return;
    int group = lane >> 4, o = lane & 15;
    int s = base[n], eend = s + cnt[n];
    float acc = 0.f;
    for (int k = s + group; k < eend; k += 4)
        acc += msg[(size_t)k * OUT_C + o];
    acc += __shfl_xor(acc, 16, 64);
    acc += __shfl_xor(acc, 32, 64);
    if (group == 0) {
        float r = bias[o];
        const float* xr = x + (size_t)n * IN_C;
        #pragma unroll
        for (int i = 0; i < IN_C; ++i)
            r = fmaf(xr[i], root[i * OUT_C + o], r);
        out[n * OUT_C + o] = r + acc;
    }
}

// ---------------- fallback path (round-2, passing) ----------------

__global__ __launch_bounds__(256) void nnconv_init_out(
    const float* __restrict__ x, const float* __restrict__ root,
    const float* __restrict__ bias, float* __restrict__ out, int n_nodes)
{
    int t = blockIdx.x * blockDim.x + threadIdx.x;
    if (t >= n_nodes * OUT_C) return;
    int n = t >> 4, o = t & 15;
    float acc = bias[o];
    #pragma unroll
    for (int i = 0; i < IN_C; ++i)
        acc = fmaf(x[n * IN_C + i], root[i * OUT_C + o], acc);
    out[t] = acc;
}

__global__ __launch_bounds__(256) void nnconv_count(
    const int* __restrict__ edge_index, int* __restrict__ cnt, int n_edges)
{
    int e = blockIdx.x * blockDim.x + threadIdx.x;
    if (e >= n_edges) return;
    atomicAdd(&cnt[edge_index[e]], 1);
}

__global__ __launch_bounds__(256) void nnconv_edge_sorted(
    const float* __restrict__ x, const int* __restrict__ edge_index,
    const float* __restrict__ pseudo,
    const float* __restrict__ W1, const float* __restrict__ b1,
    const float* __restrict__ W2, const float* __restrict__ b2,
    const int* __restrict__ base, int* __restrict__ cursor,
    float* __restrict__ msg, int n_edges)
{
    int e = blockIdx.x * blockDim.x + threadIdx.x;
    if (e >= n_edges) return;
    int row = edge_index[e];
    int col = edge_index[n_edges + e];
    float p[EDGE_DIM];
    const float4* pp = reinterpret_cast<const float4*>(pseudo + (size_t)e * EDGE_DIM);
    float4 p0 = pp[0], p1 = pp[1];
    p[0]=p0.x; p[1]=p0.y; p[2]=p0.z; p[3]=p0.w;
    p[4]=p1.x; p[5]=p1.y; p[6]=p1.z; p[7]=p1.w;
    float h[HID];
    #pragma unroll
    for (int j = 0; j < HID; ++j) {
        float a = b1[j];
        #pragma unroll
        for (int k = 0; k < EDGE_DIM; ++k)
            a = fmaf(p[k], W1[k * HID + j], a);
        h[j] = a > 0.f ? a : 0.f;
    }
    float xg[IN_C];
    const float4* xp = reinterpret_cast<const float4*>(x + (size_t)col * IN_C);
    #pragma unroll
    for (int q = 0; q < 4; ++q) {
        float4 v = xp[q];
        xg[q*4+0]=v.x; xg[q*4+1]=v.y; xg[q*4+2]=v.z; xg[q*4+3]=v.w;
    }
    float m[OUT_C];
    #pragma unroll
    for (int o = 0; o < OUT_C; ++o) m[o] = 0.f;
    for (int i = 0; i < IN_C; ++i) {
        float w[OUT_C];
        const float* b2r = b2 + i * OUT_C;
        #pragma unroll
        for (int o = 0; o < OUT_C; ++o) w[o] = b2r[o];
        #pragma unroll
        for (int j = 0; j < HID; ++j) {
            float hj = h[j];
            const float* wr = W2 + j * (IN_C * OUT_C) + i * OUT_C;
            #pragma unroll
            for (int o = 0; o < OUT_C; ++o)
                w[o] = fmaf(hj, wr[o], w[o]);
        }
        float xi = xg[i];
        #pragma unroll
        for (int o = 0; o < OUT_C; ++o)
            m[o] = fmaf(xi, w[o], m[o]);
    }
    int slot = base[row] + atomicAdd(&cursor[row], 1);
    float4* mp = reinterpret_cast<float4*>(msg + (size_t)slot * OUT_C);
    mp[0] = make_float4(m[0], m[1], m[2], m[3]);
    mp[1] = make_float4(m[4], m[5], m[6], m[7]);
    mp[2] = make_float4(m[8], m[9], m[10], m[11]);
    mp[3] = make_float4(m[12], m[13], m[14], m[15]);
}

__global__ __launch_bounds__(256) void nnconv_gather(
    const float* __restrict__ msg, const int* __restrict__ base,
    const int* __restrict__ cnt, float* __restrict__ out, int n_nodes)
{
    int wave = threadIdx.x >> 6, lane = threadIdx.x & 63;
    int n = blockIdx.x * 4 + wave;
    if (n >= n_nodes) return;
    int group = lane >> 4, o = lane & 15;
    int s = base[n], e = s + cnt[n];
    float acc = 0.f;
    for (int k = s + group; k < e; k += 4)
        acc += msg[(size_t)k * OUT_C + o];
    acc += __shfl_xor(acc, 16, 64);
    acc += __shfl_xor(acc, 32, 64);
    if (group == 0) {
        int idx = n * OUT_C + o;
        out[idx] = out[idx] + acc;
    }
}

__global__ __launch_bounds__(256) void nnconv_edge_atomic(
    const float* __restrict__ x, const int* __restrict__ edge_index,
    const float* __restrict__ pseudo,
    const float* __restrict__ W1, const float* __restrict__ b1,
    const float* __restrict__ W2, const float* __restrict__ b2,
    float* __restrict__ out, int n_edges)
{
    int e = blockIdx.x * blockDim.x + threadIdx.x;
    if (e >= n_edges) return;
    int row = edge_index[e];
    int col = edge_index[n_edges + e];
    float p[EDGE_DIM];
    const float4* pp = reinterpret_cast<const float4*>(pseudo + (size_t)e * EDGE_DIM);
    float4 p0 = pp[0], p1 = pp[1];
    p[0]=p0.x; p[1]=p0.y; p[2]=p0.z; p[3]=p0.w;
    p[4]=p1.x; p[5]=p1.y; p[6]=p1.z; p[7]=p1.w;
    float h[HID];
    #pragma unroll
    for (int j = 0; j < HID; ++j) {
        float a = b1[j];
        #pragma unroll
        for (int k = 0; k < EDGE_DIM; ++k)
            a = fmaf(p[k], W1[k * HID + j], a);
        h[j] = a > 0.f ? a : 0.f;
    }
    float xg[IN_C];
    const float4* xp = reinterpret_cast<const float4*>(x + (size_t)col * IN_C);
    #pragma unroll
    for (int q = 0; q < 4; ++q) {
        float4 v = xp[q];
        xg[q*4+0]=v.x; xg[q*4+1]=v.y; xg[q*4+2]=v.z; xg[q*4+3]=v.w;
    }
    float m[OUT_C];
    #pragma unroll
    for (int o = 0; o < OUT_C; ++o) m[o] = 0.f;
    for (int i = 0; i < IN_C; ++i) {
        float w[OUT_C];
        const float* b2r = b2 + i * OUT_C;
        #pragma unroll
        for (int o = 0; o < OUT_C; ++o) w[o] = b2r[o];
        #pragma unroll
        for (int j = 0; j < HID; ++j) {
            float hj = h[j];
            const float* wr = W2 + j * (IN_C * OUT_C) + i * OUT_C;
            #pragma unroll
            for (int o = 0; o < OUT_C; ++o)
                w[o] = fmaf(hj, wr[o], w[o]);
        }
        float xi = xg[i];
        #pragma unroll
        for (int o = 0; o < OUT_C; ++o)
            m[o] = fmaf(xi, w[o], m[o]);
    }
    float* op = out + (size_t)row * OUT_C;
    #pragma unroll
    for (int o = 0; o < OUT_C; ++o)
        atomicAdd(op + o, m[o]);
}

// ---------------- launch ----------------

extern "C" void kernel_launch(void* const* d_in, const int* in_sizes, int n_in,
                              void* d_out, int out_size, void* d_ws, size_t ws_size,
                              hipStream_t stream) {
    const float* x      = (const float*)d_in[0];
    const int*   eidx   = (const int*)  d_in[1];
    const float* pseudo = (const float*)d_in[2];
    const float* W1     = (const float*)d_in[3];
    const float* b1     = (const float*)d_in[4];
    const float* W2     = (const float*)d_in[5];
    const float* b2     = (const float*)d_in[6];
    const float* root   = (const float*)d_in[7];
    const float* bias   = (const float*)d_in[8];
    float* out = (float*)d_out;

    int n_nodes = in_sizes[0] / IN_C;
    int n_edges = in_sizes[1] / 2;
    int eblocks = (n_edges + 255) / 256;

    // full-path ws layout:
    // cnt_row[N] cnt_col[N] cur_row[N] cur_col[N] base_row[N] base_col[N] |256| packed[E] | T[N*528] | msg[E*16]
    char* wsp = (char*)d_ws;
    int* cnt_row  = (int*)wsp;
    int* cnt_col  = cnt_row + n_nodes;
    int* cur_row  = cnt_col + n_nodes;
    int* cur_col  = cur_row + n_nodes;
    int* base_row = cur_col + n_nodes;
    int* base_col = base_row + n_nodes;
    size_t off = sizeof(int) * (size_t)(6 * n_nodes);
    off = (off + 255) & ~(size_t)255;
    uint64_t* packed = (uint64_t*)(wsp + off);
    off += sizeof(uint64_t) * (size_t)n_edges;
    off = (off + 255) & ~(size_t)255;
    float* T = (float*)(wsp + off);
    off += sizeof(float) * (size_t)n_nodes * T_STRIDE;
    off = (off + 255) & ~(size_t)255;
    float* msg = (float*)(wsp + off);
    size_t need_full = off + sizeof(float) * (size_t)n_edges * OUT_C;

    bool fits_pack = (n_edges < (1 << 20)) && (n_nodes < (1 << 24));

    if (ws_size >= need_full && fits_pack) {
        nnconv_T<<<1024, 512, 0, stream>>>(x, W2, b2, T, n_nodes);
        nnconv_zero<<<128, 256, 0, stream>>>(cnt_row, 4 * n_nodes); // cnt_row..cur_col contiguous
        nnconv_count2<<<eblocks, 256, 0, stream>>>(eidx, cnt_row, cnt_col, n_edges);
        nnconv_scan2<<<2, 1024, 0, stream>>>(cnt_row, base_row, cnt_col, base_col, n_nodes);
        nnconv_build<<<eblocks, 256, 0, stream>>>(eidx, base_row, cur_row,
                                                  base_col, cur_col, packed, n_edges);
        nnconv_edge_T<<<eblocks, 256, 0, stream>>>(pseudo, W1, b1, T, packed, msg, n_edges);
        nnconv_gather_root<<<(n_nodes + 3) / 4, 256, 0, stream>>>(
            msg, base_row, cnt_row, x, root, bias, out, n_nodes);
        return;
    }

    // fallback: round-2 layout  cnt[N] base[N] cursor[N] |256| msg[E*16]
    int* cnt    = (int*)d_ws;
    int* base   = cnt + n_nodes;
    int* cursor = base + n_nodes;
    size_t hdr = sizeof(int) * (size_t)(3 * n_nodes);
    hdr = (hdr + 255) & ~(size_t)255;
    float* msg2 = (float*)((char*)d_ws + hdr);
    size_t need2 = hdr + sizeof(float) * (size_t)n_edges * OUT_C;

    nnconv_init_out<<<(n_nodes * OUT_C + 255) / 256, 256, 0, stream>>>(
        x, root, bias, out, n_nodes);

    if (ws_size < need2) {
        nnconv_edge_atomic<<<eblocks, 256, 0, stream>>>(
            x, eidx, pseudo, W1, b1, W2, b2, out, n_edges);
        return;
    }

    nnconv_zero<<<128, 256, 0, stream>>>(cnt, n_nodes);
    nnconv_zero<<<128, 256, 0, stream>>>(cursor, n_nodes);
    nnconv_count<<<eblocks, 256, 0, stream>>>(eidx, cnt, n_edges);
    nnconv_scan2<<<1, 1024, 0, stream>>>(cnt, base, cnt, base, n_nodes);
    nnconv_edge_sorted<<<eblocks, 256, 0, stream>>>(
        x, eidx, pseudo, W1, b1, W2, b2, base, cursor, msg2, n_edges);
    nnconv_gather<<<(n_nodes + 3) / 4, 256, 0, stream>>>(
        msg2, base, cnt, out, n_nodes);
}

// Round 4
// 232.319 us; speedup vs baseline: 1.0110x; 1.0110x over previous
//
#include <hip/hip_runtime.h>
#include <stdint.h>

#define IN_C   16
#define OUT_C  16
#define EDGE_DIM 8
#define HID    32
#define T_STRIDE 528   // 33*16 floats/node: j=0..31 -> sum_i x_i*W2[j,i,o]; row 32 -> sum_i x_i*b2[i,o]
#define TBLOCKS 512

// ---------------- main path ----------------

// blocks [0,TBLOCKS): T[n, j*16+o] = sum_i x[n,i]*W2[j,i*16+o]; T[n,512+o] = sum_i x[n,i]*b2[i*16+o]
// blocks [TBLOCKS, ...): histogram rows and cols
__global__ __launch_bounds__(256) void nnconv_T_count(
    const float* __restrict__ x, const float* __restrict__ W2,
    const float* __restrict__ b2, float* __restrict__ T,
    const int* __restrict__ eidx, int* __restrict__ cnt_row,
    int* __restrict__ cnt_col, int n_nodes, int n_edges)
{
    int bid = blockIdx.x;
    if (bid < TBLOCKS) {
        int t = threadIdx.x;            // 0..255 ; handles q=t and q=t+256
        int j0 = t >> 4, o = t & 15;    // q0 = t
        float w0[IN_C], w1[IN_C], wb[IN_C];
        #pragma unroll
        for (int i = 0; i < IN_C; ++i) {
            w0[i] = W2[j0 * 256 + i * 16 + o];
            w1[i] = W2[(j0 + 16) * 256 + i * 16 + o];
            wb[i] = b2[i * 16 + o];
        }
        for (int n = bid; n < n_nodes; n += TBLOCKS) {
            const float4* xp = reinterpret_cast<const float4*>(x + (size_t)n * IN_C);
            float4 x0 = xp[0], x1 = xp[1], x2 = xp[2], x3 = xp[3];
            float xv[IN_C] = {x0.x,x0.y,x0.z,x0.w, x1.x,x1.y,x1.z,x1.w,
                              x2.x,x2.y,x2.z,x2.w, x3.x,x3.y,x3.z,x3.w};
            float a0 = 0.f, a1 = 0.f, ab = 0.f;
            #pragma unroll
            for (int i = 0; i < IN_C; ++i) {
                a0 = fmaf(xv[i], w0[i], a0);
                a1 = fmaf(xv[i], w1[i], a1);
                ab = fmaf(xv[i], wb[i], ab);
            }
            float* Tn = T + (size_t)n * T_STRIDE;
            Tn[t] = a0;
            Tn[t + 256] = a1;
            if (t < 16) Tn[512 + t] = ab;
        }
    } else {
        int e = (bid - TBLOCKS) * 256 + threadIdx.x;
        if (e < n_edges) {
            atomicAdd(&cnt_row[eidx[e]], 1);
            atomicAdd(&cnt_col[eidx[n_edges + e]], 1);
        }
    }
}

// block 0: cnt_row->base_row ; block 1: cnt_col->base_col (exclusive scan)
__global__ __launch_bounds__(1024) void nnconv_scan2(
    const int* __restrict__ cnt_row, int* __restrict__ base_row,
    const int* __restrict__ cnt_col, int* __restrict__ base_col, int n)
{
    const int* cnt = (blockIdx.x == 0) ? cnt_row : cnt_col;
    int* base      = (blockIdx.x == 0) ? base_row : base_col;
    __shared__ int sums[1024];
    int t = threadIdx.x;
    int chunk = (n + 1023) >> 10;
    int lo = t * chunk; if (lo > n) lo = n;
    int hi = lo + chunk; if (hi > n) hi = n;
    int s = 0;
    for (int i = lo; i < hi; ++i) s += cnt[i];
    sums[t] = s;
    __syncthreads();
    for (int off = 1; off < 1024; off <<= 1) {
        int v = (t >= off) ? sums[t - off] : 0;
        __syncthreads();
        sums[t] += v;
        __syncthreads();
    }
    int run = sums[t] - s;
    for (int i = lo; i < hi; ++i) { base[i] = run; run += cnt[i]; }
}

// per edge: col-sorted position pc, row-sorted slot; packed[pc] = e | slot<<20 | c<<40
__global__ __launch_bounds__(256) void nnconv_build(
    const int* __restrict__ eidx,
    const int* __restrict__ base_row, int* __restrict__ cur_row,
    const int* __restrict__ base_col, int* __restrict__ cur_col,
    uint64_t* __restrict__ packed, int n_edges)
{
    int e = blockIdx.x * blockDim.x + threadIdx.x;
    if (e >= n_edges) return;
    int r = eidx[e], c = eidx[n_edges + e];
    int slot = base_row[r] + atomicAdd(&cur_row[r], 1);
    int pc   = base_col[c] + atomicAdd(&cur_col[c], 1);
    packed[pc] = (uint64_t)(uint32_t)e
               | ((uint64_t)(uint32_t)slot << 20)
               | ((uint64_t)(uint32_t)c << 40);
}

// wave per source node c: T[c] in registers, 2 edges per iteration.
// lane (g,o), g=lane>>4&3, o=lane&15: tf[k] = T[c, j=8g+k, o].
__global__ __launch_bounds__(256) void nnconv_edge_wpn(
    const float* __restrict__ pseudo,
    const float* __restrict__ W1, const float* __restrict__ b1,
    const float* __restrict__ T, const uint64_t* __restrict__ packed,
    const int* __restrict__ base_col, const int* __restrict__ cnt_col,
    float* __restrict__ msg, int n_nodes)
{
    __shared__ float hbuf[4][64];          // per-wave h for 2 edges
    int wslot = threadIdx.x >> 6;
    int lane  = threadIdx.x & 63;
    int c = (blockIdx.x << 2) + wslot;
    if (c >= n_nodes) return;
    int cnt = cnt_col[c];
    if (cnt == 0) return;                  // wave-uniform
    int s = base_col[c];

    int o = lane & 15, g = (lane >> 4) & 3;
    const float* Trow = T + (size_t)c * T_STRIDE;
    float tf[8];
    #pragma unroll
    for (int k = 0; k < 8; ++k) tf[k] = Trow[128 * g + 16 * k + o];
    float Bo = Trow[512 + o];

    int half = lane >> 5;                  // which of the 2 edges this lane's h serves
    int jl = lane & 31;
    float* hw = hbuf[wslot];

    for (int it = 0; it < cnt; it += 2) {
        int mi = it + half;
        float hval = 0.f;
        int myslot = 0;
        if (mi < cnt) {
            uint64_t pk = packed[s + mi];
            int e  = (int)(pk & 0xFFFFF);
            myslot = (int)((pk >> 20) & 0xFFFFF);
            const float* pe = pseudo + (size_t)e * EDGE_DIM;
            float a = b1[jl];
            #pragma unroll
            for (int kk = 0; kk < EDGE_DIM; ++kk)
                a = fmaf(pe[kk], W1[kk * HID + jl], a);   // broadcast loads
            hval = a > 0.f ? a : 0.f;
        }
        hw[half * 32 + jl] = hval;   // wave-coherent LDS (per-wave region, in-order DS pipe)

        // edge 0 partial: h0[8g..8g+7]
        const float4* hp0 = reinterpret_cast<const float4*>(hw + 8 * g);
        float4 ha = hp0[0], hb = hp0[1];
        float m0 = tf[0] * ha.x;
        m0 = fmaf(tf[1], ha.y, m0); m0 = fmaf(tf[2], ha.z, m0); m0 = fmaf(tf[3], ha.w, m0);
        m0 = fmaf(tf[4], hb.x, m0); m0 = fmaf(tf[5], hb.y, m0);
        m0 = fmaf(tf[6], hb.z, m0); m0 = fmaf(tf[7], hb.w, m0);
        // edge 1 partial: h1[8g..8g+7] (zeros if absent -> gated store)
        const float4* hp1 = reinterpret_cast<const float4*>(hw + 32 + 8 * g);
        float4 hc = hp1[0], hd = hp1[1];
        float m1 = tf[0] * hc.x;
        m1 = fmaf(tf[1], hc.y, m1); m1 = fmaf(tf[2], hc.z, m1); m1 = fmaf(tf[3], hc.w, m1);
        m1 = fmaf(tf[4], hd.x, m1); m1 = fmaf(tf[5], hd.y, m1);
        m1 = fmaf(tf[6], hd.z, m1); m1 = fmaf(tf[7], hd.w, m1);

        // reduce over g (lane bits 4,5)
        m0 += __shfl_xor(m0, 16, 64); m0 += __shfl_xor(m0, 32, 64);
        m1 += __shfl_xor(m1, 16, 64); m1 += __shfl_xor(m1, 32, 64);

        int slot0 = __shfl(myslot, 0, 64);
        int slot1 = __shfl(myslot, 32, 64);

        if (!(lane & 16)) {                // lanes 0..15 -> edge it, 32..47 -> edge it+1
            int m = half;
            if (it + m < cnt) {
                float v  = m ? (m1 + Bo) : (m0 + Bo);
                int   sl = m ? slot1 : slot0;
                msg[(size_t)sl * OUT_C + o] = v;
            }
        }
    }
}

// wave per node: out = bias + x@root + sum of msg slots
__global__ __launch_bounds__(256) void nnconv_gather_root(
    const float* __restrict__ msg, const int* __restrict__ base,
    const int* __restrict__ cnt, const float* __restrict__ x,
    const float* __restrict__ root, const float* __restrict__ bias,
    float* __restrict__ out, int n_nodes)
{
    int wave = threadIdx.x >> 6, lane = threadIdx.x & 63;
    int n = blockIdx.x * 4 + wave;
    if (n >= n_nodes) return;
    int group = lane >> 4, o = lane & 15;
    int s = base[n], eend = s + cnt[n];
    float acc = 0.f;
    for (int k = s + group; k < eend; k += 4)
        acc += msg[(size_t)k * OUT_C + o];
    acc += __shfl_xor(acc, 16, 64);
    acc += __shfl_xor(acc, 32, 64);
    if (group == 0) {
        float r = bias[o];
        const float* xr = x + (size_t)n * IN_C;
        #pragma unroll
        for (int i = 0; i < IN_C; ++i)
            r = fmaf(xr[i], root[i * OUT_C + o], r);
        out[n * OUT_C + o] = r + acc;
    }
}

// ---------------- fallback path (round-1 style, always fits) ----------------

__global__ __launch_bounds__(256) void nnconv_init_out(
    const float* __restrict__ x, const float* __restrict__ root,
    const float* __restrict__ bias, float* __restrict__ out, int n_nodes)
{
    int t = blockIdx.x * blockDim.x + threadIdx.x;
    if (t >= n_nodes * OUT_C) return;
    int n = t >> 4, o = t & 15;
    float acc = bias[o];
    #pragma unroll
    for (int i = 0; i < IN_C; ++i)
        acc = fmaf(x[n * IN_C + i], root[i * OUT_C + o], acc);
    out[t] = acc;
}

__global__ __launch_bounds__(256) void nnconv_edge_atomic(
    const float* __restrict__ x, const int* __restrict__ edge_index,
    const float* __restrict__ pseudo,
    const float* __restrict__ W1, const float* __restrict__ b1,
    const float* __restrict__ W2, const float* __restrict__ b2,
    float* __restrict__ out, int n_edges)
{
    int e = blockIdx.x * blockDim.x + threadIdx.x;
    if (e >= n_edges) return;
    int row = edge_index[e];
    int col = edge_index[n_edges + e];
    float p[EDGE_DIM];
    const float4* pp = reinterpret_cast<const float4*>(pseudo + (size_t)e * EDGE_DIM);
    float4 p0 = pp[0], p1 = pp[1];
    p[0]=p0.x; p[1]=p0.y; p[2]=p0.z; p[3]=p0.w;
    p[4]=p1.x; p[5]=p1.y; p[6]=p1.z; p[7]=p1.w;
    float h[HID];
    #pragma unroll
    for (int j = 0; j < HID; ++j) {
        float a = b1[j];
        #pragma unroll
        for (int k = 0; k < EDGE_DIM; ++k)
            a = fmaf(p[k], W1[k * HID + j], a);
        h[j] = a > 0.f ? a : 0.f;
    }
    float xg[IN_C];
    const float4* xp = reinterpret_cast<const float4*>(x + (size_t)col * IN_C);
    #pragma unroll
    for (int q = 0; q < 4; ++q) {
        float4 v = xp[q];
        xg[q*4+0]=v.x; xg[q*4+1]=v.y; xg[q*4+2]=v.z; xg[q*4+3]=v.w;
    }
    float m[OUT_C];
    #pragma unroll
    for (int o = 0; o < OUT_C; ++o) m[o] = 0.f;
    for (int i = 0; i < IN_C; ++i) {
        float w[OUT_C];
        const float* b2r = b2 + i * OUT_C;
        #pragma unroll
        for (int o = 0; o < OUT_C; ++o) w[o] = b2r[o];
        #pragma unroll
        for (int j = 0; j < HID; ++j) {
            float hj = h[j];
            const float* wr = W2 + j * (IN_C * OUT_C) + i * OUT_C;
            #pragma unroll
            for (int o = 0; o < OUT_C; ++o)
                w[o] = fmaf(hj, wr[o], w[o]);
        }
        float xi = xg[i];
        #pragma unroll
        for (int o = 0; o < OUT_C; ++o)
            m[o] = fmaf(xi, w[o], m[o]);
    }
    float* op = out + (size_t)row * OUT_C;
    #pragma unroll
    for (int o = 0; o < OUT_C; ++o)
        atomicAdd(op + o, m[o]);
}

// ---------------- launch ----------------

extern "C" void kernel_launch(void* const* d_in, const int* in_sizes, int n_in,
                              void* d_out, int out_size, void* d_ws, size_t ws_size,
                              hipStream_t stream) {
    const float* x      = (const float*)d_in[0];
    const int*   eidx   = (const int*)  d_in[1];
    const float* pseudo = (const float*)d_in[2];
    const float* W1     = (const float*)d_in[3];
    const float* b1     = (const float*)d_in[4];
    const float* W2     = (const float*)d_in[5];
    const float* b2     = (const float*)d_in[6];
    const float* root   = (const float*)d_in[7];
    const float* bias   = (const float*)d_in[8];
    float* out = (float*)d_out;

    int n_nodes = in_sizes[0] / IN_C;
    int n_edges = in_sizes[1] / 2;
    int eblocks = (n_edges + 255) / 256;

    // ws layout: cnt_row[N] cnt_col[N] cur_row[N] cur_col[N] base_row[N] base_col[N]
    //            |256| packed[E] |256| T[N*528] |256| msg[E*16]
    char* wsp = (char*)d_ws;
    int* cnt_row  = (int*)wsp;
    int* cnt_col  = cnt_row + n_nodes;
    int* cur_row  = cnt_col + n_nodes;
    int* cur_col  = cur_row + n_nodes;
    int* base_row = cur_col + n_nodes;
    int* base_col = base_row + n_nodes;
    size_t off = sizeof(int) * (size_t)(6 * n_nodes);
    off = (off + 255) & ~(size_t)255;
    uint64_t* packed = (uint64_t*)(wsp + off);
    off += sizeof(uint64_t) * (size_t)n_edges;
    off = (off + 255) & ~(size_t)255;
    float* T = (float*)(wsp + off);
    off += sizeof(float) * (size_t)n_nodes * T_STRIDE;
    off = (off + 255) & ~(size_t)255;
    float* msg = (float*)(wsp + off);
    size_t need_full = off + sizeof(float) * (size_t)n_edges * OUT_C;

    bool fits_pack = (n_edges < (1 << 20)) && (n_nodes < (1 << 24));

    if (ws_size >= need_full && fits_pack) {
        hipMemsetAsync(cnt_row, 0, sizeof(int) * (size_t)(4 * n_nodes), stream);
        nnconv_T_count<<<TBLOCKS + eblocks, 256, 0, stream>>>(
            x, W2, b2, T, eidx, cnt_row, cnt_col, n_nodes, n_edges);
        nnconv_scan2<<<2, 1024, 0, stream>>>(cnt_row, base_row, cnt_col, base_col, n_nodes);
        nnconv_build<<<eblocks, 256, 0, stream>>>(eidx, base_row, cur_row,
                                                  base_col, cur_col, packed, n_edges);
        nnconv_edge_wpn<<<(n_nodes + 3) / 4, 256, 0, stream>>>(
            pseudo, W1, b1, T, packed, base_col, cnt_col, msg, n_nodes);
        nnconv_gather_root<<<(n_nodes + 3) / 4, 256, 0, stream>>>(
            msg, base_row, cnt_row, x, root, bias, out, n_nodes);
        return;
    }

    nnconv_init_out<<<(n_nodes * OUT_C + 255) / 256, 256, 0, stream>>>(
        x, root, bias, out, n_nodes);
    nnconv_edge_atomic<<<eblocks, 256, 0, stream>>>(
        x, eidx, pseudo, W1, b1, W2, b2, out, n_edges);
}

// Round 5
// 210.548 us; speedup vs baseline: 1.1156x; 1.1034x over previous
//
#include <hip/hip_runtime.h>
#include <stdint.h>

#define IN_C   16
#define OUT_C  16
#define EDGE_DIM 8
#define HID    32
#define EPB    256   // edges per block in the MFMA kernel

typedef __attribute__((ext_vector_type(8))) short short8v;  // bf16x8 MFMA frag
typedef __attribute__((ext_vector_type(4))) float f32x4;

__device__ __forceinline__ uint32_t pack_bf16(float a, float b) {
    union { float f; uint32_t u; } ua, ub;
    ua.f = a; ub.f = b;
    uint32_t lo = (ua.u + 0x7FFFu + ((ua.u >> 16) & 1u)) >> 16;   // RNE
    uint32_t hi = (ub.u + 0x7FFFu + ((ub.u >> 16) & 1u)) >> 16;
    return (lo & 0xFFFFu) | (hi << 16);
}

// ---------------- aux kernels ----------------

__global__ __launch_bounds__(256) void nnconv_count(
    const int* __restrict__ eidx, int* __restrict__ cnt_row, int n_edges)
{
    int e = blockIdx.x * blockDim.x + threadIdx.x;
    if (e >= n_edges) return;
    atomicAdd(&cnt_row[eidx[e]], 1);
}

// single-block exclusive scan cnt -> base
__global__ __launch_bounds__(1024) void nnconv_scan(
    const int* __restrict__ cnt, int* __restrict__ base, int n)
{
    __shared__ int sums[1024];
    int t = threadIdx.x;
    int chunk = (n + 1023) >> 10;
    int lo = t * chunk; if (lo > n) lo = n;
    int hi = lo + chunk; if (hi > n) hi = n;
    int s = 0;
    for (int i = lo; i < hi; ++i) s += cnt[i];
    sums[t] = s;
    __syncthreads();
    for (int off = 1; off < 1024; off <<= 1) {
        int v = (t >= off) ? sums[t - off] : 0;
        __syncthreads();
        sums[t] += v;
        __syncthreads();
    }
    int run = sums[t] - s;
    for (int i = lo; i < hi; ++i) { base[i] = run; run += cnt[i]; }
}

// slot32[e] = base_row[row_e] + cursor++  (natural-order coalesced write)
__global__ __launch_bounds__(256) void nnconv_build(
    const int* __restrict__ eidx, const int* __restrict__ base_row,
    int* __restrict__ cur_row, int* __restrict__ slot32, int n_edges)
{
    int e = blockIdx.x * blockDim.x + threadIdx.x;
    if (e >= n_edges) return;
    int r = eidx[e];
    slot32[e] = base_row[r] + atomicAdd(&cur_row[r], 1);
}

// ---------------- fused MLP + MFMA GEMM + x-contraction ----------------
// msg[slot_e, o] = sum_i x[col_e, i] * ( (h_e @ W2)[i*16+o] + b2[i*16+o] )
__global__ __launch_bounds__(256) void nnconv_edge_mfma(
    const float* __restrict__ pseudo, const int* __restrict__ eidx,
    const float* __restrict__ x,
    const float* __restrict__ W1, const float* __restrict__ b1,
    const float* __restrict__ W2, const float* __restrict__ b2,
    const int* __restrict__ slot32, float* __restrict__ msg, int n_edges)
{
    __shared__ uint32_t Hlds[EPB * 36];  // bf16 pairs, 36-dword row stride (2-way-free banks)
    __shared__ float    xlds[EPB * 20];  // x[col_e][16], stride 20 floats
    __shared__ int      slds[EPB];

    int t  = threadIdx.x;
    int e0 = blockIdx.x * EPB;
    int e  = e0 + t;
    bool valid = e < n_edges;

    // ---- stage: per-edge MLP h (f32, W1/b1 wave-uniform -> scalar loads) ----
    float p[EDGE_DIM];
    if (valid) {
        const float4* pp = reinterpret_cast<const float4*>(pseudo + (size_t)e * EDGE_DIM);
        float4 p0 = pp[0], p1 = pp[1];
        p[0]=p0.x; p[1]=p0.y; p[2]=p0.z; p[3]=p0.w;
        p[4]=p1.x; p[5]=p1.y; p[6]=p1.z; p[7]=p1.w;
    } else {
        #pragma unroll
        for (int k = 0; k < EDGE_DIM; ++k) p[k] = 0.f;
    }
    float h[HID];
    #pragma unroll
    for (int j = 0; j < HID; ++j) {
        float a = b1[j];
        #pragma unroll
        for (int k = 0; k < EDGE_DIM; ++k)
            a = fmaf(p[k], W1[k * HID + j], a);
        h[j] = a > 0.f ? a : 0.f;
    }
    uint32_t hw[16];
    #pragma unroll
    for (int v = 0; v < 16; ++v) hw[v] = valid ? pack_bf16(h[2*v], h[2*v+1]) : 0u;
    uint32_t* hp = &Hlds[t * 36];
    reinterpret_cast<uint4*>(hp)[0] = make_uint4(hw[0],  hw[1],  hw[2],  hw[3]);
    reinterpret_cast<uint4*>(hp)[1] = make_uint4(hw[4],  hw[5],  hw[6],  hw[7]);
    reinterpret_cast<uint4*>(hp)[2] = make_uint4(hw[8],  hw[9],  hw[10], hw[11]);
    reinterpret_cast<uint4*>(hp)[3] = make_uint4(hw[12], hw[13], hw[14], hw[15]);

    // ---- stage: x[col_e] and slot ----
    if (valid) {
        int c = eidx[n_edges + e];
        const float4* xp = reinterpret_cast<const float4*>(x + (size_t)c * IN_C);
        float4 x0 = xp[0], x1 = xp[1], x2 = xp[2], x3 = xp[3];
        float* xd = &xlds[t * 20];
        xd[0]=x0.x; xd[1]=x0.y; xd[2]=x0.z; xd[3]=x0.w;
        xd[4]=x1.x; xd[5]=x1.y; xd[6]=x1.z; xd[7]=x1.w;
        xd[8]=x2.x; xd[9]=x2.y; xd[10]=x2.z; xd[11]=x2.w;
        xd[12]=x3.x; xd[13]=x3.y; xd[14]=x3.z; xd[15]=x3.w;
        slds[t] = slot32[e];
    } else {
        float* xd = &xlds[t * 20];
        #pragma unroll
        for (int i = 0; i < IN_C; ++i) xd[i] = 0.f;
        slds[t] = -1;
    }
    __syncthreads();

    // ---- compute: wave w handles edges [w*64, w*64+64) as 4 row-tiles ----
    int lane = t & 63, w = t >> 6;
    int o = lane & 15, g = lane >> 4;           // g = 0..3

    // B-fragments: W2 bf16, tile ci = cols [ci*16, ci*16+16), K=32
    short8v Bf[16];
    float b2v[16];
    #pragma unroll
    for (int ci = 0; ci < 16; ++ci) {
        b2v[ci] = b2[ci * 16 + o];
        uint32_t u[4];
        #pragma unroll
        for (int v = 0; v < 4; ++v) {
            int k0 = g * 8 + 2 * v;
            float blo = W2[(size_t)k0 * 256 + ci * 16 + o];
            float bhi = W2[(size_t)(k0 + 1) * 256 + ci * 16 + o];
            u[v] = pack_bf16(blo, bhi);
        }
        short8v bf;
        #pragma unroll
        for (int v = 0; v < 4; ++v) {
            bf[2*v]   = (short)(u[v] & 0xFFFFu);
            bf[2*v+1] = (short)(u[v] >> 16);
        }
        Bf[ci] = bf;
    }

    #pragma unroll
    for (int q = 0; q < 4; ++q) {
        int rt = w * 4 + q;                      // row-tile: edges rt*16..rt*16+15
        short8v A = *reinterpret_cast<const short8v*>(
            &Hlds[(size_t)(rt * 16 + o) * 36 + g * 4]);   // A row = lane&15
        float macc[4] = {0.f, 0.f, 0.f, 0.f};
        #pragma unroll
        for (int ci = 0; ci < 16; ++ci) {
            f32x4 C = __builtin_amdgcn_mfma_f32_16x16x32_bf16(
                A, Bf[ci], (f32x4){0.f, 0.f, 0.f, 0.f}, 0, 0, 0);
            #pragma unroll
            for (int r = 0; r < 4; ++r) {
                int er = rt * 16 + g * 4 + r;    // C row = (lane>>4)*4 + r
                float xv = xlds[er * 20 + ci];
                macc[r] = fmaf(xv, C[r] + b2v[ci], macc[r]);
            }
        }
        #pragma unroll
        for (int r = 0; r < 4; ++r) {
            int er = rt * 16 + g * 4 + r;
            int sl = slds[er];
            if (sl >= 0) msg[(size_t)sl * OUT_C + o] = macc[r];
        }
    }
}

// wave per node: out = bias + x@root + sum of msg slots
__global__ __launch_bounds__(256) void nnconv_gather_root(
    const float* __restrict__ msg, const int* __restrict__ base,
    const int* __restrict__ cnt, const float* __restrict__ x,
    const float* __restrict__ root, const float* __restrict__ bias,
    float* __restrict__ out, int n_nodes)
{
    int wave = threadIdx.x >> 6, lane = threadIdx.x & 63;
    int n = blockIdx.x * 4 + wave;
    if (n >= n_nodes) return;
    int group = lane >> 4, o = lane & 15;
    int s = base[n], eend = s + cnt[n];
    float acc = 0.f;
    for (int k = s + group; k < eend; k += 4)
        acc += msg[(size_t)k * OUT_C + o];
    acc += __shfl_xor(acc, 16, 64);
    acc += __shfl_xor(acc, 32, 64);
    if (group == 0) {
        float r = bias[o];
        const float* xr = x + (size_t)n * IN_C;
        #pragma unroll
        for (int i = 0; i < IN_C; ++i)
            r = fmaf(xr[i], root[i * OUT_C + o], r);
        out[n * OUT_C + o] = r + acc;
    }
}

// ---------------- fallback path (round-1 style, always fits) ----------------

__global__ __launch_bounds__(256) void nnconv_init_out(
    const float* __restrict__ x, const float* __restrict__ root,
    const float* __restrict__ bias, float* __restrict__ out, int n_nodes)
{
    int t = blockIdx.x * blockDim.x + threadIdx.x;
    if (t >= n_nodes * OUT_C) return;
    int n = t >> 4, o = t & 15;
    float acc = bias[o];
    #pragma unroll
    for (int i = 0; i < IN_C; ++i)
        acc = fmaf(x[n * IN_C + i], root[i * OUT_C + o], acc);
    out[t] = acc;
}

__global__ __launch_bounds__(256) void nnconv_edge_atomic(
    const float* __restrict__ x, const int* __restrict__ edge_index,
    const float* __restrict__ pseudo,
    const float* __restrict__ W1, const float* __restrict__ b1,
    const float* __restrict__ W2, const float* __restrict__ b2,
    float* __restrict__ out, int n_edges)
{
    int e = blockIdx.x * blockDim.x + threadIdx.x;
    if (e >= n_edges) return;
    int row = edge_index[e];
    int col = edge_index[n_edges + e];
    float p[EDGE_DIM];
    const float4* pp = reinterpret_cast<const float4*>(pseudo + (size_t)e * EDGE_DIM);
    float4 p0 = pp[0], p1 = pp[1];
    p[0]=p0.x; p[1]=p0.y; p[2]=p0.z; p[3]=p0.w;
    p[4]=p1.x; p[5]=p1.y; p[6]=p1.z; p[7]=p1.w;
    float h[HID];
    #pragma unroll
    for (int j = 0; j < HID; ++j) {
        float a = b1[j];
        #pragma unroll
        for (int k = 0; k < EDGE_DIM; ++k)
            a = fmaf(p[k], W1[k * HID + j], a);
        h[j] = a > 0.f ? a : 0.f;
    }
    float xg[IN_C];
    const float4* xp = reinterpret_cast<const float4*>(x + (size_t)col * IN_C);
    #pragma unroll
    for (int q = 0; q < 4; ++q) {
        float4 v = xp[q];
        xg[q*4+0]=v.x; xg[q*4+1]=v.y; xg[q*4+2]=v.z; xg[q*4+3]=v.w;
    }
    float m[OUT_C];
    #pragma unroll
    for (int o = 0; o < OUT_C; ++o) m[o] = 0.f;
    for (int i = 0; i < IN_C; ++i) {
        float wv[OUT_C];
        const float* b2r = b2 + i * OUT_C;
        #pragma unroll
        for (int o = 0; o < OUT_C; ++o) wv[o] = b2r[o];
        #pragma unroll
        for (int j = 0; j < HID; ++j) {
            float hj = h[j];
            const float* wr = W2 + j * (IN_C * OUT_C) + i * OUT_C;
            #pragma unroll
            for (int o = 0; o < OUT_C; ++o)
                wv[o] = fmaf(hj, wr[o], wv[o]);
        }
        float xi = xg[i];
        #pragma unroll
        for (int o = 0; o < OUT_C; ++o)
            m[o] = fmaf(xi, wv[o], m[o]);
    }
    float* op = out + (size_t)row * OUT_C;
    #pragma unroll
    for (int o = 0; o < OUT_C; ++o)
        atomicAdd(op + o, m[o]);
}

// ---------------- launch ----------------

extern "C" void kernel_launch(void* const* d_in, const int* in_sizes, int n_in,
                              void* d_out, int out_size, void* d_ws, size_t ws_size,
                              hipStream_t stream) {
    const float* x      = (const float*)d_in[0];
    const int*   eidx   = (const int*)  d_in[1];
    const float* pseudo = (const float*)d_in[2];
    const float* W1     = (const float*)d_in[3];
    const float* b1     = (const float*)d_in[4];
    const float* W2     = (const float*)d_in[5];
    const float* b2     = (const float*)d_in[6];
    const float* root   = (const float*)d_in[7];
    const float* bias   = (const float*)d_in[8];
    float* out = (float*)d_out;

    int n_nodes = in_sizes[0] / IN_C;
    int n_edges = in_sizes[1] / 2;
    int eblocks = (n_edges + 255) / 256;

    // ws layout: cnt_row[N] cur_row[N] base_row[N] |256| slot32[E] |256| msg[E*16]
    char* wsp = (char*)d_ws;
    int* cnt_row  = (int*)wsp;
    int* cur_row  = cnt_row + n_nodes;
    int* base_row = cur_row + n_nodes;
    size_t off = sizeof(int) * (size_t)(3 * n_nodes);
    off = (off + 255) & ~(size_t)255;
    int* slot32 = (int*)(wsp + off);
    off += sizeof(int) * (size_t)n_edges;
    off = (off + 255) & ~(size_t)255;
    float* msg = (float*)(wsp + off);
    size_t need = off + sizeof(float) * (size_t)n_edges * OUT_C;

    if (ws_size >= need) {
        hipMemsetAsync(cnt_row, 0, sizeof(int) * (size_t)(2 * n_nodes), stream);
        nnconv_count<<<eblocks, 256, 0, stream>>>(eidx, cnt_row, n_edges);
        nnconv_scan<<<1, 1024, 0, stream>>>(cnt_row, base_row, n_nodes);
        nnconv_build<<<eblocks, 256, 0, stream>>>(eidx, base_row, cur_row, slot32, n_edges);
        nnconv_edge_mfma<<<(n_edges + EPB - 1) / EPB, 256, 0, stream>>>(
            pseudo, eidx, x, W1, b1, W2, b2, slot32, msg, n_edges);
        nnconv_gather_root<<<(n_nodes + 3) / 4, 256, 0, stream>>>(
            msg, base_row, cnt_row, x, root, bias, out, n_nodes);
        return;
    }

    nnconv_init_out<<<(n_nodes * OUT_C + 255) / 256, 256, 0, stream>>>(
        x, root, bias, out, n_nodes);
    nnconv_edge_atomic<<<eblocks, 256, 0, stream>>>(
        x, eidx, pseudo, W1, b1, W2, b2, out, n_edges);
}

// Round 6
// 145.225 us; speedup vs baseline: 1.6173x; 1.4498x over previous
//
#include <hip/hip_runtime.h>
#include <stdint.h>

#define IN_C   16
#define OUT_C  16
#define EDGE_DIM 8
#define HID    32
#define EPB    256     // edges per block in the MFMA kernel
#define HSTR   20      // Hlds row stride in dwords (80B, 16B-aligned, banks spread)
#define XSTR   20      // xlds row stride in floats

typedef __attribute__((ext_vector_type(8))) short short8v;  // bf16x8 MFMA frag
typedef __attribute__((ext_vector_type(4))) float f32x4;

__device__ __forceinline__ uint32_t pack_bf16(float a, float b) {
    union { float f; uint32_t u; } ua, ub;
    ua.f = a; ub.f = b;
    uint32_t lo = (ua.u + 0x7FFFu + ((ua.u >> 16) & 1u)) >> 16;   // RNE
    uint32_t hi = (ub.u + 0x7FFFu + ((ub.u >> 16) & 1u)) >> 16;
    return (lo & 0xFFFFu) | (hi << 16);
}

// ---------------- aux kernels ----------------

// rank[e] = arrival order among edges sharing row_e; cnt[r] = degree
__global__ __launch_bounds__(256) void nnconv_count_rank(
    const int* __restrict__ eidx, int* __restrict__ cnt,
    int* __restrict__ rank, int n_edges)
{
    int e = blockIdx.x * blockDim.x + threadIdx.x;
    if (e >= n_edges) return;
    rank[e] = atomicAdd(&cnt[eidx[e]], 1);
}

// base[n] = allocator offset for node n's cnt[n] slots (wave-aggregated atomic)
__global__ __launch_bounds__(256) void nnconv_base_alloc(
    const int* __restrict__ cnt, int* __restrict__ base,
    int* __restrict__ total, int n)
{
    int i = blockIdx.x * blockDim.x + threadIdx.x;
    int lane = threadIdx.x & 63;
    int c = (i < n) ? cnt[i] : 0;
    int s = c;                                   // inclusive wave scan
    #pragma unroll
    for (int d = 1; d < 64; d <<= 1) {
        int v = __shfl_up(s, d, 64);
        if (lane >= d) s += v;
    }
    int wsum = __shfl(s, 63, 64);
    int wbase = 0;
    if (lane == 63) wbase = atomicAdd(total, wsum);
    wbase = __shfl(wbase, 63, 64);
    if (i < n) base[i] = wbase + s - c;
}

// ---------------- fused MLP + MFMA GEMM + x-contraction + slot ----------------
// msg[slot_e, o] = sum_i x[col_e, i] * ( (h_e @ W2)[i*16+o] + b2[i*16+o] )
__global__ __launch_bounds__(256) void nnconv_edge_mfma2(
    const float* __restrict__ pseudo, const int* __restrict__ eidx,
    const float* __restrict__ x,
    const float* __restrict__ W1, const float* __restrict__ b1,
    const float* __restrict__ W2, const float* __restrict__ b2,
    const int* __restrict__ base, const int* __restrict__ rank,
    float* __restrict__ msg, int n_edges)
{
    __shared__ uint32_t Hlds[EPB * HSTR];  // bf16 pairs
    __shared__ float    xlds[EPB * XSTR];  // x[col_e][16]
    __shared__ int      slds[EPB];

    int t  = threadIdx.x;
    int e  = blockIdx.x * EPB + t;
    bool valid = e < n_edges;

    // ---- stage: per-edge MLP h (f32; W1/b1 wave-uniform -> scalar loads) ----
    float p[EDGE_DIM];
    if (valid) {
        const float4* pp = reinterpret_cast<const float4*>(pseudo + (size_t)e * EDGE_DIM);
        float4 p0 = pp[0], p1 = pp[1];
        p[0]=p0.x; p[1]=p0.y; p[2]=p0.z; p[3]=p0.w;
        p[4]=p1.x; p[5]=p1.y; p[6]=p1.z; p[7]=p1.w;
    } else {
        #pragma unroll
        for (int k = 0; k < EDGE_DIM; ++k) p[k] = 0.f;
    }
    float h[HID];
    #pragma unroll
    for (int j = 0; j < HID; ++j) {
        float a = b1[j];
        #pragma unroll
        for (int k = 0; k < EDGE_DIM; ++k)
            a = fmaf(p[k], W1[k * HID + j], a);
        h[j] = a > 0.f ? a : 0.f;
    }
    uint32_t hw[16];
    #pragma unroll
    for (int v = 0; v < 16; ++v) hw[v] = valid ? pack_bf16(h[2*v], h[2*v+1]) : 0u;
    {
        uint4* hp = reinterpret_cast<uint4*>(&Hlds[t * HSTR]);
        hp[0] = make_uint4(hw[0],  hw[1],  hw[2],  hw[3]);
        hp[1] = make_uint4(hw[4],  hw[5],  hw[6],  hw[7]);
        hp[2] = make_uint4(hw[8],  hw[9],  hw[10], hw[11]);
        hp[3] = make_uint4(hw[12], hw[13], hw[14], hw[15]);
    }

    // ---- stage: x[col_e], slot = base[row_e] + rank[e] ----
    {
        float4* xd = reinterpret_cast<float4*>(&xlds[t * XSTR]);
        if (valid) {
            int c = eidx[n_edges + e];
            const float4* xp = reinterpret_cast<const float4*>(x + (size_t)c * IN_C);
            xd[0] = xp[0]; xd[1] = xp[1]; xd[2] = xp[2]; xd[3] = xp[3];
            slds[t] = base[eidx[e]] + rank[e];
        } else {
            float4 z = make_float4(0.f, 0.f, 0.f, 0.f);
            xd[0] = z; xd[1] = z; xd[2] = z; xd[3] = z;
            slds[t] = -1;
        }
    }
    __syncthreads();

    // ---- compute: wave w handles edges [w*64, w*64+64) as 4 row-tiles ----
    int lane = t & 63, w = t >> 6;
    int o = lane & 15, g = lane >> 4;           // g = 0..3

    // B-fragments: W2 bf16, tile ci = cols [ci*16, ci*16+16), K=32
    short8v Bf[16];
    float b2v[16];
    #pragma unroll
    for (int ci = 0; ci < 16; ++ci) {
        b2v[ci] = b2[ci * 16 + o];
        uint32_t u[4];
        #pragma unroll
        for (int v = 0; v < 4; ++v) {
            int k0 = g * 8 + 2 * v;
            float blo = W2[(size_t)k0 * 256 + ci * 16 + o];
            float bhi = W2[(size_t)(k0 + 1) * 256 + ci * 16 + o];
            u[v] = pack_bf16(blo, bhi);
        }
        short8v bf;
        #pragma unroll
        for (int v = 0; v < 4; ++v) {
            bf[2*v]   = (short)(u[v] & 0xFFFFu);
            bf[2*v+1] = (short)(u[v] >> 16);
        }
        Bf[ci] = bf;
    }

    #pragma unroll
    for (int q = 0; q < 4; ++q) {
        int rt = w * 4 + q;                      // row-tile: edges rt*16..rt*16+15
        short8v A = *reinterpret_cast<const short8v*>(
            &Hlds[(size_t)(rt * 16 + o) * HSTR + g * 4]);   // A row = lane&15, k = g*8..g*8+7
        float macc[4] = {0.f, 0.f, 0.f, 0.f};
        #pragma unroll
        for (int ci = 0; ci < 16; ++ci) {
            f32x4 C = __builtin_amdgcn_mfma_f32_16x16x32_bf16(
                A, Bf[ci], (f32x4){0.f, 0.f, 0.f, 0.f}, 0, 0, 0);
            #pragma unroll
            for (int r = 0; r < 4; ++r) {
                int er = rt * 16 + g * 4 + r;    // C row = (lane>>4)*4 + r
                float xv = xlds[er * XSTR + ci];
                macc[r] = fmaf(xv, C[r] + b2v[ci], macc[r]);
            }
        }
        #pragma unroll
        for (int r = 0; r < 4; ++r) {
            int er = rt * 16 + g * 4 + r;
            int sl = slds[er];
            if (sl >= 0) msg[(size_t)sl * OUT_C + o] = macc[r];
        }
    }
}

// wave per node: out = bias + x@root + sum of msg slots
__global__ __launch_bounds__(256) void nnconv_gather_root(
    const float* __restrict__ msg, const int* __restrict__ base,
    const int* __restrict__ cnt, const float* __restrict__ x,
    const float* __restrict__ root, const float* __restrict__ bias,
    float* __restrict__ out, int n_nodes)
{
    int wave = threadIdx.x >> 6, lane = threadIdx.x & 63;
    int n = blockIdx.x * 4 + wave;
    if (n >= n_nodes) return;
    int group = lane >> 4, o = lane & 15;
    int s = base[n], eend = s + cnt[n];
    float acc = 0.f;
    for (int k = s + group; k < eend; k += 4)
        acc += msg[(size_t)k * OUT_C + o];
    acc += __shfl_xor(acc, 16, 64);
    acc += __shfl_xor(acc, 32, 64);
    if (group == 0) {
        float r = bias[o];
        const float* xr = x + (size_t)n * IN_C;
        #pragma unroll
        for (int i = 0; i < IN_C; ++i)
            r = fmaf(xr[i], root[i * OUT_C + o], r);
        out[n * OUT_C + o] = r + acc;
    }
}

// ---------------- fallback path ----------------

__global__ __launch_bounds__(256) void nnconv_init_out(
    const float* __restrict__ x, const float* __restrict__ root,
    const float* __restrict__ bias, float* __restrict__ out, int n_nodes)
{
    int t = blockIdx.x * blockDim.x + threadIdx.x;
    if (t >= n_nodes * OUT_C) return;
    int n = t >> 4, o = t & 15;
    float acc = bias[o];
    #pragma unroll
    for (int i = 0; i < IN_C; ++i)
        acc = fmaf(x[n * IN_C + i], root[i * OUT_C + o], acc);
    out[t] = acc;
}

__global__ __launch_bounds__(256) void nnconv_edge_atomic(
    const float* __restrict__ x, const int* __restrict__ edge_index,
    const float* __restrict__ pseudo,
    const float* __restrict__ W1, const float* __restrict__ b1,
    const float* __restrict__ W2, const float* __restrict__ b2,
    float* __restrict__ out, int n_edges)
{
    int e = blockIdx.x * blockDim.x + threadIdx.x;
    if (e >= n_edges) return;
    int row = edge_index[e];
    int col = edge_index[n_edges + e];
    float p[EDGE_DIM];
    const float4* pp = reinterpret_cast<const float4*>(pseudo + (size_t)e * EDGE_DIM);
    float4 p0 = pp[0], p1 = pp[1];
    p[0]=p0.x; p[1]=p0.y; p[2]=p0.z; p[3]=p0.w;
    p[4]=p1.x; p[5]=p1.y; p[6]=p1.z; p[7]=p1.w;
    float h[HID];
    #pragma unroll
    for (int j = 0; j < HID; ++j) {
        float a = b1[j];
        #pragma unroll
        for (int k = 0; k < EDGE_DIM; ++k)
            a = fmaf(p[k], W1[k * HID + j], a);
        h[j] = a > 0.f ? a : 0.f;
    }
    float xg[IN_C];
    const float4* xp = reinterpret_cast<const float4*>(x + (size_t)col * IN_C);
    #pragma unroll
    for (int q = 0; q < 4; ++q) {
        float4 v = xp[q];
        xg[q*4+0]=v.x; xg[q*4+1]=v.y; xg[q*4+2]=v.z; xg[q*4+3]=v.w;
    }
    float m[OUT_C];
    #pragma unroll
    for (int o = 0; o < OUT_C; ++o) m[o] = 0.f;
    for (int i = 0; i < IN_C; ++i) {
        float wv[OUT_C];
        const float* b2r = b2 + i * OUT_C;
        #pragma unroll
        for (int o = 0; o < OUT_C; ++o) wv[o] = b2r[o];
        #pragma unroll
        for (int j = 0; j < HID; ++j) {
            float hj = h[j];
            const float* wr = W2 + j * (IN_C * OUT_C) + i * OUT_C;
            #pragma unroll
            for (int o = 0; o < OUT_C; ++o)
                wv[o] = fmaf(hj, wr[o], wv[o]);
        }
        float xi = xg[i];
        #pragma unroll
        for (int o = 0; o < OUT_C; ++o)
            m[o] = fmaf(xi, wv[o], m[o]);
    }
    float* op = out + (size_t)row * OUT_C;
    #pragma unroll
    for (int o = 0; o < OUT_C; ++o)
        atomicAdd(op + o, m[o]);
}

// ---------------- launch ----------------

extern "C" void kernel_launch(void* const* d_in, const int* in_sizes, int n_in,
                              void* d_out, int out_size, void* d_ws, size_t ws_size,
                              hipStream_t stream) {
    const float* x      = (const float*)d_in[0];
    const int*   eidx   = (const int*)  d_in[1];
    const float* pseudo = (const float*)d_in[2];
    const float* W1     = (const float*)d_in[3];
    const float* b1     = (const float*)d_in[4];
    const float* W2     = (const float*)d_in[5];
    const float* b2     = (const float*)d_in[6];
    const float* root   = (const float*)d_in[7];
    const float* bias   = (const float*)d_in[8];
    float* out = (float*)d_out;

    int n_nodes = in_sizes[0] / IN_C;
    int n_edges = in_sizes[1] / 2;
    int eblocks = (n_edges + 255) / 256;

    // ws layout: cnt[N] total[64] | base[N] |256| rank[E] |256| msg[E*16]
    char* wsp = (char*)d_ws;
    int* cnt   = (int*)wsp;
    int* total = cnt + n_nodes;          // 64 ints (only [0] used)
    int* base  = total + 64;
    size_t off = sizeof(int) * (size_t)(2 * n_nodes + 64);
    off = (off + 255) & ~(size_t)255;
    int* rank = (int*)(wsp + off);
    off += sizeof(int) * (size_t)n_edges;
    off = (off + 255) & ~(size_t)255;
    float* msg = (float*)(wsp + off);
    size_t need = off + sizeof(float) * (size_t)n_edges * OUT_C;

    if (ws_size >= need) {
        hipMemsetAsync(cnt, 0, sizeof(int) * (size_t)(n_nodes + 64), stream);
        nnconv_count_rank<<<eblocks, 256, 0, stream>>>(eidx, cnt, rank, n_edges);
        nnconv_base_alloc<<<(n_nodes + 255) / 256, 256, 0, stream>>>(
            cnt, base, total, n_nodes);
        nnconv_edge_mfma2<<<(n_edges + EPB - 1) / EPB, 256, 0, stream>>>(
            pseudo, eidx, x, W1, b1, W2, b2, base, rank, msg, n_edges);
        nnconv_gather_root<<<(n_nodes + 3) / 4, 256, 0, stream>>>(
            msg, base, cnt, x, root, bias, out, n_nodes);
        return;
    }

    nnconv_init_out<<<(n_nodes * OUT_C + 255) / 256, 256, 0, stream>>>(
        x, root, bias, out, n_nodes);
    nnconv_edge_atomic<<<eblocks, 256, 0, stream>>>(
        x, eidx, pseudo, W1, b1, W2, b2, out, n_edges);
}

// Round 7
// 139.552 us; speedup vs baseline: 1.6831x; 1.0407x over previous
//
#include <hip/hip_runtime.h>
#include <stdint.h>

#define IN_C   16
#define OUT_C  16
#define EDGE_DIM 8
#define HID    32
#define EPB    256     // edges per block in the MFMA kernel
#define HSTR   20      // Hlds row stride in dwords
#define XSTR   20      // xlds row stride in floats

typedef __attribute__((ext_vector_type(8))) short short8v;  // bf16x8 MFMA frag
typedef __attribute__((ext_vector_type(4))) float f32x4;

__device__ __forceinline__ uint32_t pack_bf16(float a, float b) {
    union { float f; uint32_t u; } ua, ub;
    ua.f = a; ub.f = b;
    uint32_t lo = (ua.u + 0x7FFFu + ((ua.u >> 16) & 1u)) >> 16;   // RNE
    uint32_t hi = (ub.u + 0x7FFFu + ((ub.u >> 16) & 1u)) >> 16;
    return (lo & 0xFFFFu) | (hi << 16);
}

// ---------------- aux kernels ----------------

// rank[e] = arrival order among edges sharing row_e; cnt[r] = degree
__global__ __launch_bounds__(256) void nnconv_count_rank(
    const int* __restrict__ eidx, int* __restrict__ cnt,
    int* __restrict__ rank, int n_edges)
{
    int e = blockIdx.x * blockDim.x + threadIdx.x;
    if (e >= n_edges) return;
    rank[e] = atomicAdd(&cnt[eidx[e]], 1);
}

// base[n] = allocator offset for node n's cnt[n] slots (wave-aggregated atomic)
__global__ __launch_bounds__(256) void nnconv_base_alloc(
    const int* __restrict__ cnt, int* __restrict__ base,
    int* __restrict__ total, int n)
{
    int i = blockIdx.x * blockDim.x + threadIdx.x;
    int lane = threadIdx.x & 63;
    int c = (i < n) ? cnt[i] : 0;
    int s = c;                                   // inclusive wave scan
    #pragma unroll
    for (int d = 1; d < 64; d <<= 1) {
        int v = __shfl_up(s, d, 64);
        if (lane >= d) s += v;
    }
    int wsum = __shfl(s, 63, 64);
    int wbase = 0;
    if (lane == 63) wbase = atomicAdd(total, wsum);
    wbase = __shfl(wbase, 63, 64);
    if (i < n) base[i] = wbase + s - c;
}

// pre-pack W2 (32x256 f32) into per-lane MFMA B-fragments, bf16.
// W2p[(ci*64 + l)] (uint4): lane l=(g*16+o) gets k=g*8..g*8+7 of column ci*16+o.
__global__ __launch_bounds__(256) void nnconv_packW2(
    const float* __restrict__ W2, uint4* __restrict__ W2p)
{
    int idx = blockIdx.x * 256 + threadIdx.x;   // 0..1023 = ci*64 + l
    if (idx >= 1024) return;
    int ci = idx >> 6, l = idx & 63;
    int o = l & 15, g = l >> 4;
    uint32_t u[4];
    #pragma unroll
    for (int v = 0; v < 4; ++v) {
        int k0 = g * 8 + 2 * v;
        u[v] = pack_bf16(W2[(size_t)k0 * 256 + ci * 16 + o],
                         W2[(size_t)(k0 + 1) * 256 + ci * 16 + o]);
    }
    W2p[idx] = make_uint4(u[0], u[1], u[2], u[3]);
}

// ---------------- fused MLP + MFMA GEMM + x-contraction + slot ----------------
__global__ __launch_bounds__(256) void nnconv_edge_mfma3(
    const float* __restrict__ pseudo, const int* __restrict__ eidx,
    const float* __restrict__ x,
    const float* __restrict__ W1, const float* __restrict__ b1,
    const uint4* __restrict__ W2p, const float* __restrict__ b2,
    const int* __restrict__ base, const int* __restrict__ rank,
    float* __restrict__ msg, int n_edges)
{
    __shared__ uint32_t Hlds[EPB * HSTR];  // bf16 pairs
    __shared__ float    xlds[EPB * XSTR];  // x[col_e][16]
    __shared__ int      slds[EPB];

    int t  = threadIdx.x;
    int e  = blockIdx.x * EPB + t;
    bool valid = e < n_edges;

    // ---- stage: per-edge MLP h (f32; W1/b1 wave-uniform -> scalar loads) ----
    float p[EDGE_DIM];
    if (valid) {
        const float4* pp = reinterpret_cast<const float4*>(pseudo + (size_t)e * EDGE_DIM);
        float4 p0 = pp[0], p1 = pp[1];
        p[0]=p0.x; p[1]=p0.y; p[2]=p0.z; p[3]=p0.w;
        p[4]=p1.x; p[5]=p1.y; p[6]=p1.z; p[7]=p1.w;
    } else {
        #pragma unroll
        for (int k = 0; k < EDGE_DIM; ++k) p[k] = 0.f;
    }
    float h[HID];
    #pragma unroll
    for (int j = 0; j < HID; ++j) {
        float a = b1[j];
        #pragma unroll
        for (int k = 0; k < EDGE_DIM; ++k)
            a = fmaf(p[k], W1[k * HID + j], a);
        h[j] = a > 0.f ? a : 0.f;
    }
    uint32_t hw[16];
    #pragma unroll
    for (int v = 0; v < 16; ++v) hw[v] = valid ? pack_bf16(h[2*v], h[2*v+1]) : 0u;
    {
        uint4* hp = reinterpret_cast<uint4*>(&Hlds[t * HSTR]);
        hp[0] = make_uint4(hw[0],  hw[1],  hw[2],  hw[3]);
        hp[1] = make_uint4(hw[4],  hw[5],  hw[6],  hw[7]);
        hp[2] = make_uint4(hw[8],  hw[9],  hw[10], hw[11]);
        hp[3] = make_uint4(hw[12], hw[13], hw[14], hw[15]);
    }

    // ---- stage: x[col_e], slot = base[row_e] + rank[e] ----
    {
        float4* xd = reinterpret_cast<float4*>(&xlds[t * XSTR]);
        if (valid) {
            int c = eidx[n_edges + e];
            const float4* xp = reinterpret_cast<const float4*>(x + (size_t)c * IN_C);
            xd[0] = xp[0]; xd[1] = xp[1]; xd[2] = xp[2]; xd[3] = xp[3];
            slds[t] = base[eidx[e]] + rank[e];
        } else {
            float4 z = make_float4(0.f, 0.f, 0.f, 0.f);
            xd[0] = z; xd[1] = z; xd[2] = z; xd[3] = z;
            slds[t] = -1;
        }
    }

    int lane = t & 63, w = t >> 6;
    int o = lane & 15, g = lane >> 4;

    // B-fragments: one coalesced 16B load per ci (same for all blocks, L1/L2-hot)
    short8v Bf[16];
    #pragma unroll
    for (int ci = 0; ci < 16; ++ci)
        Bf[ci] = reinterpret_cast<const short8v*>(W2p)[ci * 64 + lane];
    float b2v[16];
    #pragma unroll
    for (int ci = 0; ci < 16; ++ci) b2v[ci] = b2[ci * 16 + o];

    __syncthreads();

    // ---- compute: wave w handles edges [w*64, w*64+64) as 4 row-tiles ----
    #pragma unroll
    for (int q = 0; q < 4; ++q) {
        int rt = w * 4 + q;                      // row-tile: edges rt*16..rt*16+15
        short8v A = *reinterpret_cast<const short8v*>(
            &Hlds[(size_t)(rt * 16 + o) * HSTR + g * 4]);   // A row = lane&15
        float macc[4] = {0.f, 0.f, 0.f, 0.f};
        #pragma unroll
        for (int c4 = 0; c4 < 4; ++c4) {
            f32x4 C0 = __builtin_amdgcn_mfma_f32_16x16x32_bf16(A, Bf[c4*4+0], (f32x4){0.f,0.f,0.f,0.f}, 0, 0, 0);
            f32x4 C1 = __builtin_amdgcn_mfma_f32_16x16x32_bf16(A, Bf[c4*4+1], (f32x4){0.f,0.f,0.f,0.f}, 0, 0, 0);
            f32x4 C2 = __builtin_amdgcn_mfma_f32_16x16x32_bf16(A, Bf[c4*4+2], (f32x4){0.f,0.f,0.f,0.f}, 0, 0, 0);
            f32x4 C3 = __builtin_amdgcn_mfma_f32_16x16x32_bf16(A, Bf[c4*4+3], (f32x4){0.f,0.f,0.f,0.f}, 0, 0, 0);
            #pragma unroll
            for (int r = 0; r < 4; ++r) {
                int er = rt * 16 + g * 4 + r;    // C row = (lane>>4)*4 + r
                float4 xv = *reinterpret_cast<const float4*>(&xlds[er * XSTR + c4 * 4]);
                macc[r] = fmaf(xv.x, C0[r] + b2v[c4*4+0], macc[r]);
                macc[r] = fmaf(xv.y, C1[r] + b2v[c4*4+1], macc[r]);
                macc[r] = fmaf(xv.z, C2[r] + b2v[c4*4+2], macc[r]);
                macc[r] = fmaf(xv.w, C3[r] + b2v[c4*4+3], macc[r]);
            }
        }
        #pragma unroll
        for (int r = 0; r < 4; ++r) {
            int er = rt * 16 + g * 4 + r;
            int sl = slds[er];
            if (sl >= 0) msg[(size_t)sl * OUT_C + o] = macc[r];
        }
    }
}

// wave per node: out = bias + x@root + sum of msg slots
__global__ __launch_bounds__(256) void nnconv_gather_root(
    const float* __restrict__ msg, const int* __restrict__ base,
    const int* __restrict__ cnt, const float* __restrict__ x,
    const float* __restrict__ root, const float* __restrict__ bias,
    float* __restrict__ out, int n_nodes)
{
    int wave = threadIdx.x >> 6, lane = threadIdx.x & 63;
    int n = blockIdx.x * 4 + wave;
    if (n >= n_nodes) return;
    int group = lane >> 4, o = lane & 15;
    int s = base[n], eend = s + cnt[n];
    float acc = 0.f;
    for (int k = s + group; k < eend; k += 4)
        acc += msg[(size_t)k * OUT_C + o];
    acc += __shfl_xor(acc, 16, 64);
    acc += __shfl_xor(acc, 32, 64);
    if (group == 0) {
        float r = bias[o];
        const float* xr = x + (size_t)n * IN_C;
        #pragma unroll
        for (int i = 0; i < IN_C; ++i)
            r = fmaf(xr[i], root[i * OUT_C + o], r);
        out[n * OUT_C + o] = r + acc;
    }
}

// ---------------- fallback path ----------------

__global__ __launch_bounds__(256) void nnconv_init_out(
    const float* __restrict__ x, const float* __restrict__ root,
    const float* __restrict__ bias, float* __restrict__ out, int n_nodes)
{
    int t = blockIdx.x * blockDim.x + threadIdx.x;
    if (t >= n_nodes * OUT_C) return;
    int n = t >> 4, o = t & 15;
    float acc = bias[o];
    #pragma unroll
    for (int i = 0; i < IN_C; ++i)
        acc = fmaf(x[n * IN_C + i], root[i * OUT_C + o], acc);
    out[t] = acc;
}

__global__ __launch_bounds__(256) void nnconv_edge_atomic(
    const float* __restrict__ x, const int* __restrict__ edge_index,
    const float* __restrict__ pseudo,
    const float* __restrict__ W1, const float* __restrict__ b1,
    const float* __restrict__ W2, const float* __restrict__ b2,
    float* __restrict__ out, int n_edges)
{
    int e = blockIdx.x * blockDim.x + threadIdx.x;
    if (e >= n_edges) return;
    int row = edge_index[e];
    int col = edge_index[n_edges + e];
    float p[EDGE_DIM];
    const float4* pp = reinterpret_cast<const float4*>(pseudo + (size_t)e * EDGE_DIM);
    float4 p0 = pp[0], p1 = pp[1];
    p[0]=p0.x; p[1]=p0.y; p[2]=p0.z; p[3]=p0.w;
    p[4]=p1.x; p[5]=p1.y; p[6]=p1.z; p[7]=p1.w;
    float h[HID];
    #pragma unroll
    for (int j = 0; j < HID; ++j) {
        float a = b1[j];
        #pragma unroll
        for (int k = 0; k < EDGE_DIM; ++k)
            a = fmaf(p[k], W1[k * HID + j], a);
        h[j] = a > 0.f ? a : 0.f;
    }
    float xg[IN_C];
    const float4* xp = reinterpret_cast<const float4*>(x + (size_t)col * IN_C);
    #pragma unroll
    for (int q = 0; q < 4; ++q) {
        float4 v = xp[q];
        xg[q*4+0]=v.x; xg[q*4+1]=v.y; xg[q*4+2]=v.z; xg[q*4+3]=v.w;
    }
    float m[OUT_C];
    #pragma unroll
    for (int o = 0; o < OUT_C; ++o) m[o] = 0.f;
    for (int i = 0; i < IN_C; ++i) {
        float wv[OUT_C];
        const float* b2r = b2 + i * OUT_C;
        #pragma unroll
        for (int o = 0; o < OUT_C; ++o) wv[o] = b2r[o];
        #pragma unroll
        for (int j = 0; j < HID; ++j) {
            float hj = h[j];
            const float* wr = W2 + j * (IN_C * OUT_C) + i * OUT_C;
            #pragma unroll
            for (int o = 0; o < OUT_C; ++o)
                wv[o] = fmaf(hj, wr[o], wv[o]);
        }
        float xi = xg[i];
        #pragma unroll
        for (int o = 0; o < OUT_C; ++o)
            m[o] = fmaf(xi, wv[o], m[o]);
    }
    float* op = out + (size_t)row * OUT_C;
    #pragma unroll
    for (int o = 0; o < OUT_C; ++o)
        atomicAdd(op + o, m[o]);
}

// ---------------- launch ----------------

extern "C" void kernel_launch(void* const* d_in, const int* in_sizes, int n_in,
                              void* d_out, int out_size, void* d_ws, size_t ws_size,
                              hipStream_t stream) {
    const float* x      = (const float*)d_in[0];
    const int*   eidx   = (const int*)  d_in[1];
    const float* pseudo = (const float*)d_in[2];
    const float* W1     = (const float*)d_in[3];
    const float* b1     = (const float*)d_in[4];
    const float* W2     = (const float*)d_in[5];
    const float* b2     = (const float*)d_in[6];
    const float* root   = (const float*)d_in[7];
    const float* bias   = (const float*)d_in[8];
    float* out = (float*)d_out;

    int n_nodes = in_sizes[0] / IN_C;
    int n_edges = in_sizes[1] / 2;
    int eblocks = (n_edges + 255) / 256;

    // ws layout: cnt[N] total[64] base[N] |256| W2p[1024 uint4] | rank[E] |256| msg[E*16]
    char* wsp = (char*)d_ws;
    int* cnt   = (int*)wsp;
    int* total = cnt + n_nodes;          // 64 ints (only [0] used)
    int* base  = total + 64;
    size_t off = sizeof(int) * (size_t)(2 * n_nodes + 64);
    off = (off + 255) & ~(size_t)255;
    uint4* W2p = (uint4*)(wsp + off);
    off += sizeof(uint4) * 1024;
    int* rank = (int*)(wsp + off);
    off += sizeof(int) * (size_t)n_edges;
    off = (off + 255) & ~(size_t)255;
    float* msg = (float*)(wsp + off);
    size_t need = off + sizeof(float) * (size_t)n_edges * OUT_C;

    if (ws_size >= need) {
        hipMemsetAsync(cnt, 0, sizeof(int) * (size_t)(n_nodes + 64), stream);
        nnconv_packW2<<<4, 256, 0, stream>>>(W2, W2p);
        nnconv_count_rank<<<eblocks, 256, 0, stream>>>(eidx, cnt, rank, n_edges);
        nnconv_base_alloc<<<(n_nodes + 255) / 256, 256, 0, stream>>>(
            cnt, base, total, n_nodes);
        nnconv_edge_mfma3<<<(n_edges + EPB - 1) / EPB, 256, 0, stream>>>(
            pseudo, eidx, x, W1, b1, W2p, b2, base, rank, msg, n_edges);
        nnconv_gather_root<<<(n_nodes + 3) / 4, 256, 0, stream>>>(
            msg, base, cnt, x, root, bias, out, n_nodes);
        return;
    }

    nnconv_init_out<<<(n_nodes * OUT_C + 255) / 256, 256, 0, stream>>>(
        x, root, bias, out, n_nodes);
    nnconv_edge_atomic<<<eblocks, 256, 0, stream>>>(
        x, eidx, pseudo, W1, b1, W2, b2, out, n_edges);
}

// Round 8
// 127.753 us; speedup vs baseline: 1.8385x; 1.0924x over previous
//
#include <hip/hip_runtime.h>
#include <stdint.h>

#define IN_C   16
#define OUT_C  16
#define EDGE_DIM 8
#define HID    32
#define EPB    256     // edges per block in the GEMM kernel
#define XSTR   20      // xlds row stride in floats

typedef __attribute__((ext_vector_type(8))) short short8v;  // bf16x8 MFMA frag
typedef __attribute__((ext_vector_type(4))) float f32x4;

__device__ __forceinline__ uint32_t pack_bf16(float a, float b) {
    union { float f; uint32_t u; } ua, ub;
    ua.f = a; ub.f = b;
    uint32_t lo = (ua.u + 0x7FFFu + ((ua.u >> 16) & 1u)) >> 16;   // RNE
    uint32_t hi = (ub.u + 0x7FFFu + ((ub.u >> 16) & 1u)) >> 16;
    return (lo & 0xFFFFu) | (hi << 16);
}

// ---------------- aux kernels ----------------

// base[n] = allocator offset for node n's cnt[n] slots (wave-aggregated atomic)
__global__ __launch_bounds__(256) void nnconv_base_alloc(
    const int* __restrict__ cnt, int* __restrict__ base,
    int* __restrict__ total, int n)
{
    int i = blockIdx.x * blockDim.x + threadIdx.x;
    int lane = threadIdx.x & 63;
    int c = (i < n) ? cnt[i] : 0;
    int s = c;                                   // inclusive wave scan
    #pragma unroll
    for (int d = 1; d < 64; d <<= 1) {
        int v = __shfl_up(s, d, 64);
        if (lane >= d) s += v;
    }
    int wsum = __shfl(s, 63, 64);
    int wbase = 0;
    if (lane == 63) wbase = atomicAdd(total, wsum);
    wbase = __shfl(wbase, 63, 64);
    if (i < n) base[i] = wbase + s - c;
}

// pre-pack W2 (32x256 f32) into per-lane MFMA B-fragments, bf16.
__global__ __launch_bounds__(256) void nnconv_packW2(
    const float* __restrict__ W2, uint4* __restrict__ W2p)
{
    int idx = blockIdx.x * 256 + threadIdx.x;   // 0..1023 = ci*64 + l
    if (idx >= 1024) return;
    int ci = idx >> 6, l = idx & 63;
    int o = l & 15, g = l >> 4;
    uint32_t u[4];
    #pragma unroll
    for (int v = 0; v < 4; ++v) {
        int k0 = g * 8 + 2 * v;
        u[v] = pack_bf16(W2[(size_t)k0 * 256 + ci * 16 + o],
                         W2[(size_t)(k0 + 1) * 256 + ci * 16 + o]);
    }
    W2p[idx] = make_uint4(u[0], u[1], u[2], u[3]);
}

// blocks [0, eblocks): per-edge MLP -> packed bf16 H rows (64B/edge, coalesced)
// blocks [eblocks, 2*eblocks): rank[e] = atomicAdd(&cnt[row_e], 1)
__global__ __launch_bounds__(256) void nnconv_mlp_count(
    const float* __restrict__ pseudo, const int* __restrict__ eidx,
    const float* __restrict__ W1, const float* __restrict__ b1,
    uint4* __restrict__ Hp, int* __restrict__ cnt, int* __restrict__ rank,
    int n_edges, int eblocks)
{
    int bid = blockIdx.x;
    int t = threadIdx.x;
    if (bid < eblocks) {
        int e = bid * 256 + t;
        bool valid = e < n_edges;
        float p[EDGE_DIM];
        if (valid) {
            const float4* pp = reinterpret_cast<const float4*>(pseudo + (size_t)e * EDGE_DIM);
            float4 p0 = pp[0], p1 = pp[1];
            p[0]=p0.x; p[1]=p0.y; p[2]=p0.z; p[3]=p0.w;
            p[4]=p1.x; p[5]=p1.y; p[6]=p1.z; p[7]=p1.w;
        } else {
            #pragma unroll
            for (int k = 0; k < EDGE_DIM; ++k) p[k] = 0.f;
        }
        uint32_t hw[16];
        #pragma unroll
        for (int j2 = 0; j2 < 16; ++j2) {   // pairs of hidden units
            float a0 = b1[2*j2], a1 = b1[2*j2+1];
            #pragma unroll
            for (int k = 0; k < EDGE_DIM; ++k) {
                a0 = fmaf(p[k], W1[k * HID + 2*j2],   a0);
                a1 = fmaf(p[k], W1[k * HID + 2*j2+1], a1);
            }
            a0 = a0 > 0.f ? a0 : 0.f;
            a1 = a1 > 0.f ? a1 : 0.f;
            hw[j2] = valid ? pack_bf16(a0, a1) : 0u;
        }
        uint4* hp = Hp + (size_t)(bid * 256 + t) * 4;
        hp[0] = make_uint4(hw[0],  hw[1],  hw[2],  hw[3]);
        hp[1] = make_uint4(hw[4],  hw[5],  hw[6],  hw[7]);
        hp[2] = make_uint4(hw[8],  hw[9],  hw[10], hw[11]);
        hp[3] = make_uint4(hw[12], hw[13], hw[14], hw[15]);
    } else {
        int e = (bid - eblocks) * 256 + t;
        if (e < n_edges)
            rank[e] = atomicAdd(&cnt[eidx[e]], 1);
    }
}

// ---------------- GEMM + x-contraction + scatter-slot ----------------
// msg[slot_e, o] = sum_ci x[col_e, ci] * ( (h_e @ W2)[ci*16+o] + b2[ci*16+o] )
__global__ __launch_bounds__(256) void nnconv_gemm(
    const uint4* __restrict__ Hp, const int* __restrict__ eidx,
    const float* __restrict__ x,
    const uint4* __restrict__ W2p, const float* __restrict__ b2,
    const int* __restrict__ base, const int* __restrict__ rank,
    float* __restrict__ msg, int n_edges)
{
    __shared__ float xlds[EPB * XSTR];  // x[col_e][16]
    __shared__ int   slds[EPB];

    int t  = threadIdx.x;
    int e0 = blockIdx.x * EPB;
    int e  = e0 + t;
    bool valid = e < n_edges;

    // ---- stage: x[col_e] -> LDS, slot = base[row_e] + rank[e] ----
    {
        float4* xd = reinterpret_cast<float4*>(&xlds[t * XSTR]);
        if (valid) {
            int c = eidx[n_edges + e];
            const float4* xp = reinterpret_cast<const float4*>(x + (size_t)c * IN_C);
            xd[0] = xp[0]; xd[1] = xp[1]; xd[2] = xp[2]; xd[3] = xp[3];
            slds[t] = base[eidx[e]] + rank[e];
        } else {
            float4 z = make_float4(0.f, 0.f, 0.f, 0.f);
            xd[0] = z; xd[1] = z; xd[2] = z; xd[3] = z;
            slds[t] = -1;
        }
    }

    int lane = t & 63, w = t >> 6;
    int o = lane & 15, g = lane >> 4;

    // A-fragments straight from global Hp (rows are padded: reads always valid)
    short8v A[4];
    #pragma unroll
    for (int q = 0; q < 4; ++q) {
        int row = e0 + (w * 4 + q) * 16 + o;
        A[q] = reinterpret_cast<const short8v*>(Hp)[(size_t)row * 4 + g];
    }
    float b2v[16];
    #pragma unroll
    for (int ci = 0; ci < 16; ++ci) b2v[ci] = b2[ci * 16 + o];

    __syncthreads();

    float macc[4][4];
    #pragma unroll
    for (int q = 0; q < 4; ++q)
        #pragma unroll
        for (int r = 0; r < 4; ++r) macc[q][r] = 0.f;

    #pragma unroll
    for (int hf = 0; hf < 2; ++hf) {
        short8v Bf[8];
        #pragma unroll
        for (int j = 0; j < 8; ++j)
            Bf[j] = reinterpret_cast<const short8v*>(W2p)[(hf * 8 + j) * 64 + lane];
        #pragma unroll
        for (int q = 0; q < 4; ++q) {
            f32x4 C[8];
            #pragma unroll
            for (int j = 0; j < 8; ++j) {
                float bb = b2v[hf * 8 + j];
                C[j] = __builtin_amdgcn_mfma_f32_16x16x32_bf16(
                    A[q], Bf[j], (f32x4){bb, bb, bb, bb}, 0, 0, 0);
            }
            #pragma unroll
            for (int r = 0; r < 4; ++r) {
                int er = (w * 4 + q) * 16 + g * 4 + r;
                float4 xa = *reinterpret_cast<const float4*>(&xlds[er * XSTR + hf * 8]);
                float4 xb = *reinterpret_cast<const float4*>(&xlds[er * XSTR + hf * 8 + 4]);
                float m = macc[q][r];
                m = fmaf(xa.x, C[0][r], m); m = fmaf(xa.y, C[1][r], m);
                m = fmaf(xa.z, C[2][r], m); m = fmaf(xa.w, C[3][r], m);
                m = fmaf(xb.x, C[4][r], m); m = fmaf(xb.y, C[5][r], m);
                m = fmaf(xb.z, C[6][r], m); m = fmaf(xb.w, C[7][r], m);
                macc[q][r] = m;
            }
        }
    }

    #pragma unroll
    for (int q = 0; q < 4; ++q)
        #pragma unroll
        for (int r = 0; r < 4; ++r) {
            int er = (w * 4 + q) * 16 + g * 4 + r;
            int sl = slds[er];
            if (sl >= 0) msg[(size_t)sl * OUT_C + o] = macc[q][r];
        }
}

// wave per node: out = bias + x@root + sum of msg slots
__global__ __launch_bounds__(256) void nnconv_gather_root(
    const float* __restrict__ msg, const int* __restrict__ base,
    const int* __restrict__ cnt, const float* __restrict__ x,
    const float* __restrict__ root, const float* __restrict__ bias,
    float* __restrict__ out, int n_nodes)
{
    int wave = threadIdx.x >> 6, lane = threadIdx.x & 63;
    int n = blockIdx.x * 4 + wave;
    if (n >= n_nodes) return;
    int group = lane >> 4, o = lane & 15;
    int s = base[n], eend = s + cnt[n];
    float acc = 0.f;
    for (int k = s + group; k < eend; k += 4)
        acc += msg[(size_t)k * OUT_C + o];
    acc += __shfl_xor(acc, 16, 64);
    acc += __shfl_xor(acc, 32, 64);
    if (group == 0) {
        float r = bias[o];
        const float* xr = x + (size_t)n * IN_C;
        #pragma unroll
        for (int i = 0; i < IN_C; ++i)
            r = fmaf(xr[i], root[i * OUT_C + o], r);
        out[n * OUT_C + o] = r + acc;
    }
}

// ---------------- fallback path ----------------

__global__ __launch_bounds__(256) void nnconv_init_out(
    const float* __restrict__ x, const float* __restrict__ root,
    const float* __restrict__ bias, float* __restrict__ out, int n_nodes)
{
    int t = blockIdx.x * blockDim.x + threadIdx.x;
    if (t >= n_nodes * OUT_C) return;
    int n = t >> 4, o = t & 15;
    float acc = bias[o];
    #pragma unroll
    for (int i = 0; i < IN_C; ++i)
        acc = fmaf(x[n * IN_C + i], root[i * OUT_C + o], acc);
    out[t] = acc;
}

__global__ __launch_bounds__(256) void nnconv_edge_atomic(
    const float* __restrict__ x, const int* __restrict__ edge_index,
    const float* __restrict__ pseudo,
    const float* __restrict__ W1, const float* __restrict__ b1,
    const float* __restrict__ W2, const float* __restrict__ b2,
    float* __restrict__ out, int n_edges)
{
    int e = blockIdx.x * blockDim.x + threadIdx.x;
    if (e >= n_edges) return;
    int row = edge_index[e];
    int col = edge_index[n_edges + e];
    float p[EDGE_DIM];
    const float4* pp = reinterpret_cast<const float4*>(pseudo + (size_t)e * EDGE_DIM);
    float4 p0 = pp[0], p1 = pp[1];
    p[0]=p0.x; p[1]=p0.y; p[2]=p0.z; p[3]=p0.w;
    p[4]=p1.x; p[5]=p1.y; p[6]=p1.z; p[7]=p1.w;
    float h[HID];
    #pragma unroll
    for (int j = 0; j < HID; ++j) {
        float a = b1[j];
        #pragma unroll
        for (int k = 0; k < EDGE_DIM; ++k)
            a = fmaf(p[k], W1[k * HID + j], a);
        h[j] = a > 0.f ? a : 0.f;
    }
    float xg[IN_C];
    const float4* xp = reinterpret_cast<const float4*>(x + (size_t)col * IN_C);
    #pragma unroll
    for (int q = 0; q < 4; ++q) {
        float4 v = xp[q];
        xg[q*4+0]=v.x; xg[q*4+1]=v.y; xg[q*4+2]=v.z; xg[q*4+3]=v.w;
    }
    float m[OUT_C];
    #pragma unroll
    for (int o = 0; o < OUT_C; ++o) m[o] = 0.f;
    for (int i = 0; i < IN_C; ++i) {
        float wv[OUT_C];
        const float* b2r = b2 + i * OUT_C;
        #pragma unroll
        for (int o = 0; o < OUT_C; ++o) wv[o] = b2r[o];
        #pragma unroll
        for (int j = 0; j < HID; ++j) {
            float hj = h[j];
            const float* wr = W2 + j * (IN_C * OUT_C) + i * OUT_C;
            #pragma unroll
            for (int o = 0; o < OUT_C; ++o)
                wv[o] = fmaf(hj, wr[o], wv[o]);
        }
        float xi = xg[i];
        #pragma unroll
        for (int o = 0; o < OUT_C; ++o)
            m[o] = fmaf(xi, wv[o], m[o]);
    }
    float* op = out + (size_t)row * OUT_C;
    #pragma unroll
    for (int o = 0; o < OUT_C; ++o)
        atomicAdd(op + o, m[o]);
}

// ---------------- launch ----------------

extern "C" void kernel_launch(void* const* d_in, const int* in_sizes, int n_in,
                              void* d_out, int out_size, void* d_ws, size_t ws_size,
                              hipStream_t stream) {
    const float* x      = (const float*)d_in[0];
    const int*   eidx   = (const int*)  d_in[1];
    const float* pseudo = (const float*)d_in[2];
    const float* W1     = (const float*)d_in[3];
    const float* b1     = (const float*)d_in[4];
    const float* W2     = (const float*)d_in[5];
    const float* b2     = (const float*)d_in[6];
    const float* root   = (const float*)d_in[7];
    const float* bias   = (const float*)d_in[8];
    float* out = (float*)d_out;

    int n_nodes = in_sizes[0] / IN_C;
    int n_edges = in_sizes[1] / 2;
    int eblocks = (n_edges + EPB - 1) / EPB;
    size_t Epad = (size_t)eblocks * EPB;

    // ws layout: cnt[N] total[64] base[N] |256| W2p[1024 u4] | Hp[Epad*4 u4] | rank[E] |256| msg[E*16]
    char* wsp = (char*)d_ws;
    int* cnt   = (int*)wsp;
    int* total = cnt + n_nodes;          // 64 ints (only [0] used)
    int* base  = total + 64;
    size_t off = sizeof(int) * (size_t)(2 * n_nodes + 64);
    off = (off + 255) & ~(size_t)255;
    uint4* W2p = (uint4*)(wsp + off);
    off += sizeof(uint4) * 1024;
    uint4* Hp = (uint4*)(wsp + off);
    off += sizeof(uint4) * Epad * 4;
    int* rank = (int*)(wsp + off);
    off += sizeof(int) * (size_t)n_edges;
    off = (off + 255) & ~(size_t)255;
    float* msg = (float*)(wsp + off);
    size_t need = off + sizeof(float) * (size_t)n_edges * OUT_C;

    if (ws_size >= need) {
        hipMemsetAsync(cnt, 0, sizeof(int) * (size_t)(n_nodes + 64), stream);
        nnconv_packW2<<<4, 256, 0, stream>>>(W2, W2p);
        nnconv_mlp_count<<<2 * eblocks, 256, 0, stream>>>(
            pseudo, eidx, W1, b1, Hp, cnt, rank, n_edges, eblocks);
        nnconv_base_alloc<<<(n_nodes + 255) / 256, 256, 0, stream>>>(
            cnt, base, total, n_nodes);
        nnconv_gemm<<<eblocks, 256, 0, stream>>>(
            Hp, eidx, x, W2p, b2, base, rank, msg, n_edges);
        nnconv_gather_root<<<(n_nodes + 3) / 4, 256, 0, stream>>>(
            msg, base, cnt, x, root, bias, out, n_nodes);
        return;
    }

    nnconv_init_out<<<(n_nodes * OUT_C + 255) / 256, 256, 0, stream>>>(
        x, root, bias, out, n_nodes);
    nnconv_edge_atomic<<<eblocks, 256, 0, stream>>>(
        x, eidx, pseudo, W1, b1, W2, b2, out, n_edges);
}

// Round 9
// 124.798 us; speedup vs baseline: 1.8821x; 1.0237x over previous
//
#include <hip/hip_runtime.h>
#include <stdint.h>

#define IN_C   16
#define OUT_C  16
#define EDGE_DIM 8
#define HID    32
#define XSTR   20      // xl row stride in floats

typedef __attribute__((ext_vector_type(8))) short short8v;  // bf16x8 MFMA frag
typedef __attribute__((ext_vector_type(4))) float f32x4;

__device__ __forceinline__ uint32_t pack_bf16(float a, float b) {
    union { float f; uint32_t u; } ua, ub;
    ua.f = a; ub.f = b;
    uint32_t lo = (ua.u + 0x7FFFu + ((ua.u >> 16) & 1u)) >> 16;   // RNE
    uint32_t hi = (ub.u + 0x7FFFu + ((ub.u >> 16) & 1u)) >> 16;
    return (lo & 0xFFFFu) | (hi << 16);
}

// ---------------- aux kernels ----------------

// base[n] = allocator offset for node n's cnt[n] slots (wave-aggregated atomic)
__global__ __launch_bounds__(256) void nnconv_base_alloc(
    const int* __restrict__ cnt, int* __restrict__ base,
    int* __restrict__ total, int n)
{
    int i = blockIdx.x * blockDim.x + threadIdx.x;
    int lane = threadIdx.x & 63;
    int c = (i < n) ? cnt[i] : 0;
    int s = c;                                   // inclusive wave scan
    #pragma unroll
    for (int d = 1; d < 64; d <<= 1) {
        int v = __shfl_up(s, d, 64);
        if (lane >= d) s += v;
    }
    int wsum = __shfl(s, 63, 64);
    int wbase = 0;
    if (lane == 63) wbase = atomicAdd(total, wsum);
    wbase = __shfl(wbase, 63, 64);
    if (i < n) base[i] = wbase + s - c;
}

// pre-pack W2 (32x256 f32) into per-lane MFMA B-fragments, bf16.
__global__ __launch_bounds__(256) void nnconv_packW2(
    const float* __restrict__ W2, uint4* __restrict__ W2p)
{
    int idx = blockIdx.x * 256 + threadIdx.x;   // 0..1023 = ci*64 + l
    if (idx >= 1024) return;
    int ci = idx >> 6, l = idx & 63;
    int o = l & 15, g = l >> 4;
    uint32_t u[4];
    #pragma unroll
    for (int v = 0; v < 4; ++v) {
        int k0 = g * 8 + 2 * v;
        u[v] = pack_bf16(W2[(size_t)k0 * 256 + ci * 16 + o],
                         W2[(size_t)(k0 + 1) * 256 + ci * 16 + o]);
    }
    W2p[idx] = make_uint4(u[0], u[1], u[2], u[3]);
}

// per-edge MLP -> packed bf16 H rows (64B/edge, coalesced) + NON-RETURNING count
__global__ __launch_bounds__(256) void nnconv_mlp_count(
    const float* __restrict__ pseudo, const int* __restrict__ eidx,
    const float* __restrict__ W1, const float* __restrict__ b1,
    uint4* __restrict__ Hp, int* __restrict__ cnt, int n_edges)
{
    int e = blockIdx.x * 256 + threadIdx.x;
    bool valid = e < n_edges;
    float p[EDGE_DIM];
    if (valid) {
        const float4* pp = reinterpret_cast<const float4*>(pseudo + (size_t)e * EDGE_DIM);
        float4 p0 = pp[0], p1 = pp[1];
        p[0]=p0.x; p[1]=p0.y; p[2]=p0.z; p[3]=p0.w;
        p[4]=p1.x; p[5]=p1.y; p[6]=p1.z; p[7]=p1.w;
    } else {
        #pragma unroll
        for (int k = 0; k < EDGE_DIM; ++k) p[k] = 0.f;
    }
    // k-outer / j-inner: W1 row k is 32 consecutive floats -> s_load_dwordx16 x2
    float h[HID];
    #pragma unroll
    for (int j = 0; j < HID; ++j) h[j] = b1[j];
    #pragma unroll
    for (int k = 0; k < EDGE_DIM; ++k) {
        float pk = p[k];
        const float* wr = W1 + k * HID;
        #pragma unroll
        for (int j = 0; j < HID; ++j)
            h[j] = fmaf(pk, wr[j], h[j]);
    }
    uint32_t hw[16];
    #pragma unroll
    for (int v = 0; v < 16; ++v) {
        float a0 = h[2*v]   > 0.f ? h[2*v]   : 0.f;
        float a1 = h[2*v+1] > 0.f ? h[2*v+1] : 0.f;
        hw[v] = valid ? pack_bf16(a0, a1) : 0u;
    }
    uint4* hp = Hp + (size_t)e * 4;
    hp[0] = make_uint4(hw[0],  hw[1],  hw[2],  hw[3]);
    hp[1] = make_uint4(hw[4],  hw[5],  hw[6],  hw[7]);
    hp[2] = make_uint4(hw[8],  hw[9],  hw[10], hw[11]);
    hp[3] = make_uint4(hw[12], hw[13], hw[14], hw[15]);
    if (valid)
        atomicAdd(&cnt[eidx[e]], 1);    // result unused -> fire-and-forget
}

// ---------------- GEMM + x-contraction + hidden-latency slot atomic ----------------
// one wave per block; wave handles 64 edges as 4 16-row tiles
__global__ __launch_bounds__(64) void nnconv_gemm(
    const uint4* __restrict__ Hp, const int* __restrict__ eidx,
    const float* __restrict__ x,
    const uint4* __restrict__ W2p, const float* __restrict__ b2,
    const int* __restrict__ base, int* __restrict__ cur,
    float* __restrict__ msg, int n_edges)
{
    __shared__ float xl[64 * XSTR];

    int t  = threadIdx.x;               // lane
    int e0 = blockIdx.x * 64;
    int e  = e0 + t;
    bool valid = e < n_edges;

    // early: returning atomic issued NOW, first consumed after all compute
    int slv = -1;
    if (valid) {
        int r = eidx[e];
        slv = base[r] + atomicAdd(&cur[r], 1);
        int c = eidx[n_edges + e];
        float4* xd = reinterpret_cast<float4*>(&xl[t * XSTR]);
        const float4* xp = reinterpret_cast<const float4*>(x + (size_t)c * IN_C);
        xd[0] = xp[0]; xd[1] = xp[1]; xd[2] = xp[2]; xd[3] = xp[3];
    } else {
        float4* xd = reinterpret_cast<float4*>(&xl[t * XSTR]);
        float4 z = make_float4(0.f, 0.f, 0.f, 0.f);
        xd[0] = z; xd[1] = z; xd[2] = z; xd[3] = z;
    }

    int o = t & 15, g = t >> 4;

    // A-fragments straight from global Hp (rows padded to 256-multiple)
    short8v A[4];
    #pragma unroll
    for (int q = 0; q < 4; ++q)
        A[q] = reinterpret_cast<const short8v*>(Hp)[(size_t)(e0 + q * 16 + o) * 4 + g];
    float b2v[16];
    #pragma unroll
    for (int ci = 0; ci < 16; ++ci) b2v[ci] = b2[ci * 16 + o];

    __syncthreads();

    float macc[4][4];
    #pragma unroll
    for (int q = 0; q < 4; ++q)
        #pragma unroll
        for (int r = 0; r < 4; ++r) macc[q][r] = 0.f;

    #pragma unroll
    for (int hf = 0; hf < 2; ++hf) {
        short8v Bf[8];
        #pragma unroll
        for (int j = 0; j < 8; ++j)
            Bf[j] = reinterpret_cast<const short8v*>(W2p)[(hf * 8 + j) * 64 + t];
        #pragma unroll
        for (int q = 0; q < 4; ++q) {
            f32x4 C[8];
            #pragma unroll
            for (int j = 0; j < 8; ++j) {
                float bb = b2v[hf * 8 + j];
                C[j] = __builtin_amdgcn_mfma_f32_16x16x32_bf16(
                    A[q], Bf[j], (f32x4){bb, bb, bb, bb}, 0, 0, 0);
            }
            #pragma unroll
            for (int r = 0; r < 4; ++r) {
                int el = q * 16 + g * 4 + r;      // local edge index 0..63
                float4 xa = *reinterpret_cast<const float4*>(&xl[el * XSTR + hf * 8]);
                float4 xb = *reinterpret_cast<const float4*>(&xl[el * XSTR + hf * 8 + 4]);
                float m = macc[q][r];
                m = fmaf(xa.x, C[0][r], m); m = fmaf(xa.y, C[1][r], m);
                m = fmaf(xa.z, C[2][r], m); m = fmaf(xa.w, C[3][r], m);
                m = fmaf(xb.x, C[4][r], m); m = fmaf(xb.y, C[5][r], m);
                m = fmaf(xb.z, C[6][r], m); m = fmaf(xb.w, C[7][r], m);
                macc[q][r] = m;
            }
        }
    }

    // slots via in-wave shuffle of the (by now long-landed) atomic results
    #pragma unroll
    for (int q = 0; q < 4; ++q)
        #pragma unroll
        for (int r = 0; r < 4; ++r) {
            int el = q * 16 + g * 4 + r;
            int sl = __shfl(slv, el, 64);
            if (sl >= 0) msg[(size_t)sl * OUT_C + o] = macc[q][r];
        }
}

// wave per node: out = bias + x@root + sum of msg slots
__global__ __launch_bounds__(256) void nnconv_gather_root(
    const float* __restrict__ msg, const int* __restrict__ base,
    const int* __restrict__ cnt, const float* __restrict__ x,
    const float* __restrict__ root, const float* __restrict__ bias,
    float* __restrict__ out, int n_nodes)
{
    int wave = threadIdx.x >> 6, lane = threadIdx.x & 63;
    int n = blockIdx.x * 4 + wave;
    if (n >= n_nodes) return;
    int group = lane >> 4, o = lane & 15;
    int s = base[n], eend = s + cnt[n];
    float acc = 0.f;
    for (int k = s + group; k < eend; k += 4)
        acc += msg[(size_t)k * OUT_C + o];
    acc += __shfl_xor(acc, 16, 64);
    acc += __shfl_xor(acc, 32, 64);
    if (group == 0) {
        float r = bias[o];
        const float* xr = x + (size_t)n * IN_C;
        #pragma unroll
        for (int i = 0; i < IN_C; ++i)
            r = fmaf(xr[i], root[i * OUT_C + o], r);
        out[n * OUT_C + o] = r + acc;
    }
}

// ---------------- fallback path ----------------

__global__ __launch_bounds__(256) void nnconv_init_out(
    const float* __restrict__ x, const float* __restrict__ root,
    const float* __restrict__ bias, float* __restrict__ out, int n_nodes)
{
    int t = blockIdx.x * blockDim.x + threadIdx.x;
    if (t >= n_nodes * OUT_C) return;
    int n = t >> 4, o = t & 15;
    float acc = bias[o];
    #pragma unroll
    for (int i = 0; i < IN_C; ++i)
        acc = fmaf(x[n * IN_C + i], root[i * OUT_C + o], acc);
    out[t] = acc;
}

__global__ __launch_bounds__(256) void nnconv_edge_atomic(
    const float* __restrict__ x, const int* __restrict__ edge_index,
    const float* __restrict__ pseudo,
    const float* __restrict__ W1, const float* __restrict__ b1,
    const float* __restrict__ W2, const float* __restrict__ b2,
    float* __restrict__ out, int n_edges)
{
    int e = blockIdx.x * blockDim.x + threadIdx.x;
    if (e >= n_edges) return;
    int row = edge_index[e];
    int col = edge_index[n_edges + e];
    float p[EDGE_DIM];
    const float4* pp = reinterpret_cast<const float4*>(pseudo + (size_t)e * EDGE_DIM);
    float4 p0 = pp[0], p1 = pp[1];
    p[0]=p0.x; p[1]=p0.y; p[2]=p0.z; p[3]=p0.w;
    p[4]=p1.x; p[5]=p1.y; p[6]=p1.z; p[7]=p1.w;
    float h[HID];
    #pragma unroll
    for (int j = 0; j < HID; ++j) {
        float a = b1[j];
        #pragma unroll
        for (int k = 0; k < EDGE_DIM; ++k)
            a = fmaf(p[k], W1[k * HID + j], a);
        h[j] = a > 0.f ? a : 0.f;
    }
    float xg[IN_C];
    const float4* xp = reinterpret_cast<const float4*>(x + (size_t)col * IN_C);
    #pragma unroll
    for (int q = 0; q < 4; ++q) {
        float4 v = xp[q];
        xg[q*4+0]=v.x; xg[q*4+1]=v.y; xg[q*4+2]=v.z; xg[q*4+3]=v.w;
    }
    float m[OUT_C];
    #pragma unroll
    for (int o = 0; o < OUT_C; ++o) m[o] = 0.f;
    for (int i = 0; i < IN_C; ++i) {
        float wv[OUT_C];
        const float* b2r = b2 + i * OUT_C;
        #pragma unroll
        for (int o = 0; o < OUT_C; ++o) wv[o] = b2r[o];
        #pragma unroll
        for (int j = 0; j < HID; ++j) {
            float hj = h[j];
            const float* wr = W2 + j * (IN_C * OUT_C) + i * OUT_C;
            #pragma unroll
            for (int o = 0; o < OUT_C; ++o)
                wv[o] = fmaf(hj, wr[o], wv[o]);
        }
        float xi = xg[i];
        #pragma unroll
        for (int o = 0; o < OUT_C; ++o)
            m[o] = fmaf(xi, wv[o], m[o]);
    }
    float* op = out + (size_t)row * OUT_C;
    #pragma unroll
    for (int o = 0; o < OUT_C; ++o)
        atomicAdd(op + o, m[o]);
}

// ---------------- launch ----------------

extern "C" void kernel_launch(void* const* d_in, const int* in_sizes, int n_in,
                              void* d_out, int out_size, void* d_ws, size_t ws_size,
                              hipStream_t stream) {
    const float* x      = (const float*)d_in[0];
    const int*   eidx   = (const int*)  d_in[1];
    const float* pseudo = (const float*)d_in[2];
    const float* W1     = (const float*)d_in[3];
    const float* b1     = (const float*)d_in[4];
    const float* W2     = (const float*)d_in[5];
    const float* b2     = (const float*)d_in[6];
    const float* root   = (const float*)d_in[7];
    const float* bias   = (const float*)d_in[8];
    float* out = (float*)d_out;

    int n_nodes = in_sizes[0] / IN_C;
    int n_edges = in_sizes[1] / 2;
    int eblocks256 = (n_edges + 255) / 256;
    int gblocks    = (n_edges + 63) / 64;
    size_t Epad = (size_t)eblocks256 * 256;

    // ws layout: cnt[N] cur[N] total[64] base[N] |256| W2p[1024 u4] | Hp[Epad*4 u4] |256| msg[E*16]
    char* wsp = (char*)d_ws;
    int* cnt   = (int*)wsp;
    int* cur   = cnt + n_nodes;
    int* total = cur + n_nodes;          // 64 ints (only [0] used)
    int* base  = total + 64;
    size_t off = sizeof(int) * (size_t)(3 * n_nodes + 64);
    off = (off + 255) & ~(size_t)255;
    uint4* W2p = (uint4*)(wsp + off);
    off += sizeof(uint4) * 1024;
    uint4* Hp = (uint4*)(wsp + off);
    off += sizeof(uint4) * Epad * 4;
    off = (off + 255) & ~(size_t)255;
    float* msg = (float*)(wsp + off);
    size_t need = off + sizeof(float) * (size_t)n_edges * OUT_C;

    if (ws_size >= need) {
        hipMemsetAsync(cnt, 0, sizeof(int) * (size_t)(2 * n_nodes + 64), stream);
        nnconv_packW2<<<4, 256, 0, stream>>>(W2, W2p);
        nnconv_mlp_count<<<eblocks256, 256, 0, stream>>>(
            pseudo, eidx, W1, b1, Hp, cnt, n_edges);
        nnconv_base_alloc<<<(n_nodes + 255) / 256, 256, 0, stream>>>(
            cnt, base, total, n_nodes);
        nnconv_gemm<<<gblocks, 64, 0, stream>>>(
            Hp, eidx, x, W2p, b2, base, cur, msg, n_edges);
        nnconv_gather_root<<<(n_nodes + 3) / 4, 256, 0, stream>>>(
            msg, base, cnt, x, root, bias, out, n_nodes);
        return;
    }

    nnconv_init_out<<<(n_nodes * OUT_C + 255) / 256, 256, 0, stream>>>(
        x, root, bias, out, n_nodes);
    nnconv_edge_atomic<<<eblocks256, 256, 0, stream>>>(
        x, eidx, pseudo, W1, b1, W2, b2, out, n_edges);
}